// Round 20
// baseline (253.279 us; speedup 1.0000x reference)
//
#include <hip/hip_runtime.h>
#include <math.h>

#define D 128
#define HEADS 4
#define DK 32
#define NUM_HE 20000
#define BIN_CH 4096

typedef short bf16x8 __attribute__((ext_vector_type(8)));
typedef float f32x4  __attribute__((ext_vector_type(4)));

__device__ __forceinline__ unsigned short f2bf(float f) {
    unsigned int u = __float_as_uint(f);
    u = (u + 0x7fffu + ((u >> 16) & 1u)) >> 16;
    return (unsigned short)u;
}
__device__ __forceinline__ float bf2f(unsigned short h) {
    return __uint_as_float(((unsigned int)h) << 16);
}
__device__ __forceinline__ float bflo(unsigned int u) {
    return __uint_as_float(u << 16);
}
__device__ __forceinline__ float bfhi(unsigned int u) {
    return __uint_as_float(u & 0xffff0000u);
}
__device__ __forceinline__ unsigned int packbf(float lo, float hi) {
    return (unsigned int)f2bf(lo) | ((unsigned int)f2bf(hi) << 16);
}
// raw v_exp_f32: computes 2^x in one VALU instruction (ISA §3)
__device__ __forceinline__ float fexp2(float x) {
    float r;
    asm("v_exp_f32 %0, %1" : "=v"(r) : "v"(x));
    return r;
}
// butterfly add over 8-lane groups via DPP (VALU pipe, no LDS)
template<int CTRL>
__device__ __forceinline__ float dppadd(float v) {
    int s = __builtin_amdgcn_update_dpp(0, __float_as_int(v), CTRL, 0xf, 0xf, true);
    return v + __int_as_float(s);
}
__device__ __forceinline__ float red8(float v) {
    v = dppadd<0xB1>(v);    // quad_perm [1,0,3,2]  (xor 1)
    v = dppadd<0x4E>(v);    // quad_perm [2,3,0,1]  (xor 2)
    v = dppadd<0x141>(v);   // row_half_mirror      (xor 4 equivalent)
    return v;
}

// ---------------------------------------------------------------------------
// W preprocessing: fragment-order Wk|Wq|Wa as bf16 hi/lo.
// ---------------------------------------------------------------------------
__global__ void wprep(const float* __restrict__ Wk, const float* __restrict__ Wq,
                      const float* __restrict__ Wa, unsigned short* __restrict__ dst)
{
    int t = blockIdx.x * blockDim.x + threadIdx.x;
    if (t >= 3 * 16384) return;
    int w = t >> 14, rem = t & 16383;
    int ks = rem >> 12, nf = (rem >> 9) & 7, lane = (rem >> 3) & 63, j = rem & 7;
    int r = ks * 32 + (lane >> 4) * 8 + j;
    int c = nf * 16 + (lane & 15);
    const float* W = (w == 0) ? Wk : (w == 1) ? Wq : Wa;
    float v = W[r * 128 + c];
    unsigned short h = f2bf(v);
    dst[(size_t)w * 32768 + rem]         = h;
    dst[(size_t)w * 32768 + 16384 + rem] = f2bf(v - bf2f(h));
}

// ---------------------------------------------------------------------------
// Fused K+Q projection (R9 structure). K path 1 MFMA; Q path 3-MFMA split.
// Epilogue: per-wave LDS tile (XOR col swizzle) -> coalesced 256B-row stores.
// ---------------------------------------------------------------------------
__global__ __launch_bounds__(256) void gemm_kq(
    const float* __restrict__ A,
    const unsigned short* __restrict__ BhK,
    const unsigned short* __restrict__ BhQ, const unsigned short* __restrict__ BlQ,
    const float* __restrict__ bk, const float* __restrict__ bq,
    unsigned short* __restrict__ K, unsigned short* __restrict__ Q, int M)
{
    __shared__ unsigned short tile[4][32][128];   // 32 KB, per-wave 8 KB
    const int lane = threadIdx.x & 63;
    const int wv   = threadIdx.x >> 6;
    const int r0   = blockIdx.x * 128 + wv * 32;
    const int lr   = lane & 15;
    const int kg   = lane >> 4;
    unsigned short (*mytile)[128] = tile[wv];

    f32x4 ack[2][8], acq[2][8];
    #pragma unroll
    for (int m = 0; m < 2; ++m)
        #pragma unroll
        for (int n = 0; n < 8; ++n) {
            ack[m][n] = (f32x4){0.f, 0.f, 0.f, 0.f};
            acq[m][n] = (f32x4){0.f, 0.f, 0.f, 0.f};
        }

    int row[2];
    row[0] = min(r0 + lr,      M - 1);
    row[1] = min(r0 + 16 + lr, M - 1);

    for (int ks = 0; ks < 4; ++ks) {
        bf16x8 ah[2], al[2];
        #pragma unroll
        for (int m = 0; m < 2; ++m) {
            const float* p = A + (size_t)row[m] * D + ks * 32 + kg * 8;
            float4 v0 = *(const float4*)p;
            float4 v1 = *(const float4*)(p + 4);
            float vv[8] = {v0.x, v0.y, v0.z, v0.w, v1.x, v1.y, v1.z, v1.w};
            #pragma unroll
            for (int j = 0; j < 8; ++j) {
                unsigned short h = f2bf(vv[j]);
                ah[m][j] = (short)h;
                al[m][j] = (short)f2bf(vv[j] - bf2f(h));
            }
        }
        #pragma unroll
        for (int nf = 0; nf < 8; ++nf) {
            const int boff = ((ks * 8 + nf) * 64 + lane) * 8;
            bf16x8 bhk = *(const bf16x8*)(const void*)(BhK + boff);
            bf16x8 bhq = *(const bf16x8*)(const void*)(BhQ + boff);
            bf16x8 blq = *(const bf16x8*)(const void*)(BlQ + boff);
            #pragma unroll
            for (int m = 0; m < 2; ++m) {
                ack[m][nf] = __builtin_amdgcn_mfma_f32_16x16x32_bf16(ah[m], bhk, ack[m][nf], 0, 0, 0);
                acq[m][nf] = __builtin_amdgcn_mfma_f32_16x16x32_bf16(ah[m], bhq, acq[m][nf], 0, 0, 0);
                acq[m][nf] = __builtin_amdgcn_mfma_f32_16x16x32_bf16(ah[m], blq, acq[m][nf], 0, 0, 0);
                acq[m][nf] = __builtin_amdgcn_mfma_f32_16x16x32_bf16(al[m], bhq, acq[m][nf], 0, 0, 0);
            }
        }
    }

    // --- K epilogue: stage (swizzled) -> coalesced store ---
    #pragma unroll
    for (int nf = 0; nf < 8; ++nf) {
        int col = nf * 16 + lr;
        float bkv = bk[col];
        int colp = col ^ (kg << 4);
        #pragma unroll
        for (int m = 0; m < 2; ++m)
            #pragma unroll
            for (int j = 0; j < 4; ++j)
                mytile[m * 16 + kg * 4 + j][colp] = f2bf(ack[m][nf][j] + bkv);
    }
    #pragma unroll
    for (int it = 0; it < 8; ++it) {
        int idx  = it * 64 + lane;
        int lrow = idx >> 4;
        int chnk = idx & 15;
        int pch  = chnk ^ (((lrow >> 2) & 3) << 1);
        uint4 v = *(const uint4*)&mytile[lrow][pch * 8];
        int gr = r0 + lrow;
        if (gr < M) *(uint4*)(K + (size_t)gr * D + chnk * 8) = v;
    }

    // --- Q epilogue (reuse the same per-wave tile) ---
    #pragma unroll
    for (int nf = 0; nf < 8; ++nf) {
        int col = nf * 16 + lr;
        float bqv = bq[col];
        int colp = col ^ (kg << 4);
        #pragma unroll
        for (int m = 0; m < 2; ++m)
            #pragma unroll
            for (int j = 0; j < 4; ++j)
                mytile[m * 16 + kg * 4 + j][colp] = f2bf(acq[m][nf][j] + bqv);
    }
    #pragma unroll
    for (int it = 0; it < 8; ++it) {
        int idx  = it * 64 + lane;
        int lrow = idx >> 4;
        int chnk = idx & 15;
        int pch  = chnk ^ (((lrow >> 2) & 3) << 1);
        uint4 v = *(const uint4*)&mytile[lrow][pch * 8];
        int gr = r0 + lrow;
        if (gr < M) *(uint4*)(Q + (size_t)gr * D + chnk * 8) = v;
    }
}

// ---------------------------------------------------------------------------
// Output projection: A = bf16 node_out + fp32 residual x; fp32 out.
// ---------------------------------------------------------------------------
__global__ __launch_bounds__(256) void gemm_out(
    const unsigned short* __restrict__ A, const float* __restrict__ R,
    const unsigned short* __restrict__ Bh, const unsigned short* __restrict__ Bl,
    const float* __restrict__ bias, float* __restrict__ C, int M)
{
    const int lane = threadIdx.x & 63;
    const int wv   = threadIdx.x >> 6;
    const int r0   = blockIdx.x * 128 + wv * 32;
    const int lr   = lane & 15;
    const int kg   = lane >> 4;

    f32x4 acc[2][8];
    #pragma unroll
    for (int m = 0; m < 2; ++m)
        #pragma unroll
        for (int n = 0; n < 8; ++n) acc[m][n] = (f32x4){0.f, 0.f, 0.f, 0.f};

    int row[2];
    row[0] = min(r0 + lr,      M - 1);
    row[1] = min(r0 + 16 + lr, M - 1);

    for (int ks = 0; ks < 4; ++ks) {
        bf16x8 ah[2], al[2];
        #pragma unroll
        for (int m = 0; m < 2; ++m) {
            const unsigned short* pa = A + (size_t)row[m] * D + ks * 32 + kg * 8;
            uint4 av = *(const uint4*)(const void*)pa;
            const float* q = R + (size_t)row[m] * D + ks * 32 + kg * 8;
            float4 u0 = *(const float4*)q;
            float4 u1 = *(const float4*)(q + 4);
            float vv[8];
            vv[0] = bflo(av.x) + u0.x; vv[1] = bfhi(av.x) + u0.y;
            vv[2] = bflo(av.y) + u0.z; vv[3] = bfhi(av.y) + u0.w;
            vv[4] = bflo(av.z) + u1.x; vv[5] = bfhi(av.z) + u1.y;
            vv[6] = bflo(av.w) + u1.z; vv[7] = bfhi(av.w) + u1.w;
            #pragma unroll
            for (int j = 0; j < 8; ++j) {
                unsigned short h = f2bf(vv[j]);
                ah[m][j] = (short)h;
                al[m][j] = (short)f2bf(vv[j] - bf2f(h));
            }
        }
        #pragma unroll
        for (int nf = 0; nf < 8; ++nf) {
            const int boff = ((ks * 8 + nf) * 64 + lane) * 8;
            bf16x8 bh = *(const bf16x8*)(const void*)(Bh + boff);
            bf16x8 bl = *(const bf16x8*)(const void*)(Bl + boff);
            #pragma unroll
            for (int m = 0; m < 2; ++m) {
                acc[m][nf] = __builtin_amdgcn_mfma_f32_16x16x32_bf16(ah[m], bh, acc[m][nf], 0, 0, 0);
                acc[m][nf] = __builtin_amdgcn_mfma_f32_16x16x32_bf16(ah[m], bl, acc[m][nf], 0, 0, 0);
                acc[m][nf] = __builtin_amdgcn_mfma_f32_16x16x32_bf16(al[m], bh, acc[m][nf], 0, 0, 0);
            }
        }
    }

    #pragma unroll
    for (int nf = 0; nf < 8; ++nf) {
        int col = nf * 16 + lr;
        float bv = bias[col];
        #pragma unroll
        for (int m = 0; m < 2; ++m) {
            #pragma unroll
            for (int j = 0; j < 4; ++j) {
                int gr = r0 + m * 16 + kg * 4 + j;
                if (gr < M) C[(size_t)gr * D + col] = acc[m][nf][j] + bv;
            }
        }
    }
}

// ---------------------------------------------------------------------------
// Fused two-sided binning. Staging entries packed in 4 bytes:
// (seg_local << 20) | val.
// ---------------------------------------------------------------------------
__device__ __forceinline__ void lds_exscan(int* hist, int* offs, int* wtot,
                                           int nb, int tid, int lane, int wid)
{
    const int i0 = tid * 4;
    int v0 = (i0 + 0 < nb) ? hist[i0 + 0] : 0;
    int v1 = (i0 + 1 < nb) ? hist[i0 + 1] : 0;
    int v2 = (i0 + 2 < nb) ? hist[i0 + 2] : 0;
    int v3 = (i0 + 3 < nb) ? hist[i0 + 3] : 0;
    int tsum = v0 + v1 + v2 + v3;
    int x = tsum;
    #pragma unroll
    for (int off = 1; off < 64; off <<= 1) {
        int y = __shfl_up(x, off);
        if (lane >= off) x += y;
    }
    if (lane == 63) wtot[wid] = x;
    __syncthreads();
    if (tid == 0) {
        int r = 0;
        #pragma unroll
        for (int w = 0; w < 4; ++w) { int c = wtot[w]; wtot[w] = r; r += c; }
    }
    __syncthreads();
    int base = wtot[wid] + x - tsum;
    if (i0 + 0 < nb) offs[i0 + 0] = base; base += v0;
    if (i0 + 1 < nb) offs[i0 + 1] = base; base += v1;
    if (i0 + 2 < nb) offs[i0 + 2] = base; base += v2;
    if (i0 + 3 < nb) offs[i0 + 3] = base;
    __syncthreads();
}

__global__ __launch_bounds__(256) void stage_both(
    const int* __restrict__ he_idx, const int* __restrict__ nd_idx,
    int* __restrict__ counts_he, int* __restrict__ boffs_he,
    unsigned* __restrict__ staging_he,
    int* __restrict__ counts_nd, int* __restrict__ boffs_nd,
    unsigned* __restrict__ staging_nd,
    int E, int nb_he, int nb_nd)
{
    __shared__ int hist_he[640], offs_he[640];
    __shared__ int hist_nd[800], offs_nd[800];
    __shared__ int wtot[4];
    const int tid = threadIdx.x, lane = tid & 63, wid = tid >> 6;
    const int e0 = blockIdx.x * BIN_CH;

    for (int i = tid; i < nb_he; i += 256) hist_he[i] = 0;
    for (int i = tid; i < nb_nd; i += 256) hist_nd[i] = 0;
    __syncthreads();

    int myhe[16], mynd[16], rhe[16], rnd[16];
    #pragma unroll
    for (int j = 0; j < 16; ++j) {
        int e = e0 + j * 256 + tid;
        if (e < E) {
            int h = he_idx[e], n = nd_idx[e];
            myhe[j] = h; mynd[j] = n;
            rhe[j] = atomicAdd(&hist_he[h >> 5], 1);
            rnd[j] = atomicAdd(&hist_nd[n >> 7], 1);
        } else myhe[j] = -1;
    }
    __syncthreads();

    lds_exscan(hist_he, offs_he, wtot, nb_he, tid, lane, wid);
    lds_exscan(hist_nd, offs_nd, wtot, nb_nd, tid, lane, wid);

    for (int i = tid; i < nb_he; i += 256) {
        counts_he[(size_t)blockIdx.x * nb_he + i] = hist_he[i];
        boffs_he [(size_t)blockIdx.x * nb_he + i] = offs_he[i];
    }
    for (int i = tid; i < nb_nd; i += 256) {
        counts_nd[(size_t)blockIdx.x * nb_nd + i] = hist_nd[i];
        boffs_nd [(size_t)blockIdx.x * nb_nd + i] = offs_nd[i];
    }
    #pragma unroll
    for (int j = 0; j < 16; ++j) {
        if (myhe[j] >= 0) {
            int bh = myhe[j] >> 5;
            staging_he[e0 + offs_he[bh] + rhe[j]] =
                ((unsigned)(myhe[j] & 31) << 20) | (unsigned)mynd[j];
            int bn = mynd[j] >> 7;
            staging_nd[e0 + offs_nd[bn] + rnd[j]] =
                ((unsigned)(mynd[j] & 127) << 20) | (unsigned)myhe[j];
        }
    }
}

__global__ void bucket_tot2(const int* __restrict__ counts_he,
                            const int* __restrict__ counts_nd,
                            int* __restrict__ btot, int nb_he, int nb_nd, int nblk)
{
    int k = blockIdx.x * 4 + (threadIdx.x >> 6);
    if (k >= nb_he + nb_nd) return;
    int lane = threadIdx.x & 63;
    const int* counts = (k < nb_he) ? counts_he : counts_nd;
    int nb = (k < nb_he) ? nb_he : nb_nd;
    int kk = (k < nb_he) ? k : k - nb_he;
    int s = 0;
    for (int b = lane; b < nblk; b += 64) s += counts[(size_t)b * nb + kk];
    #pragma unroll
    for (int off = 1; off < 64; off <<= 1) s += __shfl_xor(s, off);
    if (lane == 0) btot[k] = s;
}

__global__ void bucket_scan2(const int* __restrict__ btot, int* __restrict__ bbase,
                             int* __restrict__ he_ptr, int* __restrict__ nd_ptr,
                             int nseg_he, int nseg_nd, int nb_he, int nb_nd, int Etot)
{
    __shared__ int wsum[16];
    const int side = blockIdx.x;
    const int nb   = side ? nb_nd : nb_he;
    const int off0 = side ? nb_he : 0;
    int* ptr       = side ? nd_ptr : he_ptr;
    const int nseg = side ? nseg_nd : nseg_he;
    const int tid = threadIdx.x, lane = tid & 63, wid = tid >> 6;
    int v = (tid < nb) ? btot[off0 + tid] : 0;
    int x = v;
    #pragma unroll
    for (int off = 1; off < 64; off <<= 1) {
        int y = __shfl_up(x, off);
        if (lane >= off) x += y;
    }
    if (lane == 63) wsum[wid] = x;
    __syncthreads();
    if (wid == 0) {
        int wv = (lane < 16) ? wsum[lane] : 0;
        #pragma unroll
        for (int off = 1; off < 16; off <<= 1) {
            int y = __shfl_up(wv, off);
            if (lane >= off) wv += y;
        }
        if (lane < 16) wsum[lane] = wv;
    }
    __syncthreads();
    int base = (wid > 0) ? wsum[wid - 1] : 0;
    if (tid < nb) bbase[off0 + tid] = base + x - v;
    if (tid == 0) ptr[nseg] = Etot;
}

template<int SHIFT>
__global__ __launch_bounds__(256) void fill_csr(
    const unsigned* __restrict__ staging, const int* __restrict__ counts,
    const int* __restrict__ boffs, const int* __restrict__ bbase,
    int* __restrict__ ptr, int* __restrict__ outv,
    int nseg, int nb, int nblk)
{
    __shared__ int cur[1 << SHIFT];
    const int tid = threadIdx.x;
    const int k   = blockIdx.x;
    const int s0  = k << SHIFT;
    const int NS  = min(1 << SHIFT, nseg - s0);
    for (int i = tid; i < NS; i += 256) cur[i] = 0;
    __syncthreads();
    for (int b = tid; b < nblk; b += 256) {
        int c   = counts[(size_t)b * nb + k];
        int off = b * BIN_CH + boffs[(size_t)b * nb + k];
        for (int i = 0; i < c; ++i) {
            int sl = (int)(staging[off + i] >> 20);
            atomicAdd(&cur[sl], 1);
        }
    }
    __syncthreads();
    if (tid == 0) {
        int run = bbase[k];
        for (int i = 0; i < NS; ++i) {
            int c = cur[i];
            cur[i] = run;
            ptr[s0 + i] = run;
            run += c;
        }
    }
    __syncthreads();
    for (int b = tid; b < nblk; b += 256) {
        int c   = counts[(size_t)b * nb + k];
        int off = b * BIN_CH + boffs[(size_t)b * nb + k];
        for (int i = 0; i < c; ++i) {
            unsigned pv = staging[off + i];
            int pos = atomicAdd(&cur[pv >> 20], 1);
            outv[pos] = (int)(pv & 0xFFFFFu);
        }
    }
}

// ---------------------------------------------------------------------------
// Stage 2: he_feat[h] = sum of member K rows (half-wave layout, CSR gather).
// 32-bit index arithmetic (all offsets < 2^25 bytes) avoids 64-bit mads.
// ---------------------------------------------------------------------------
__global__ void gather_he(const uint2* __restrict__ K2,
                          const int* __restrict__ he_ptr,
                          const int* __restrict__ members,
                          uint2* __restrict__ he_feat2, int HE)
{
    int h = blockIdx.x * 4 + (threadIdx.x >> 6);
    if (h >= HE) return;
    unsigned lane = threadIdx.x & 63;
    unsigned half = lane >> 5;
    unsigned q    = lane & 31;
    int beg = he_ptr[h], end = he_ptr[h + 1];
    float a0 = 0.f, a1 = 0.f, a2 = 0.f, a3 = 0.f;
    int p = beg;
    for (; p + 7 < end; p += 8) {
        unsigned nA = (unsigned)members[p     + half];
        unsigned nB = (unsigned)members[p + 2 + half];
        unsigned nC = (unsigned)members[p + 4 + half];
        unsigned nD = (unsigned)members[p + 6 + half];
        uint2 uA = K2[(nA << 5) + q];
        uint2 uB = K2[(nB << 5) + q];
        uint2 uC = K2[(nC << 5) + q];
        uint2 uD = K2[(nD << 5) + q];
        a0 += (bflo(uA.x) + bflo(uB.x)) + (bflo(uC.x) + bflo(uD.x));
        a1 += (bfhi(uA.x) + bfhi(uB.x)) + (bfhi(uC.x) + bfhi(uD.x));
        a2 += (bflo(uA.y) + bflo(uB.y)) + (bflo(uC.y) + bflo(uD.y));
        a3 += (bfhi(uA.y) + bfhi(uB.y)) + (bfhi(uC.y) + bfhi(uD.y));
    }
    for (; p < end; p += 2) {
        int pi = p + (int)half;
        bool valid = pi < end;
        unsigned nn = (unsigned)members[valid ? pi : beg];
        uint2 u = K2[(nn << 5) + q];
        float w = valid ? 1.f : 0.f;
        a0 += w * bflo(u.x);
        a1 += w * bfhi(u.x);
        a2 += w * bflo(u.y);
        a3 += w * bfhi(u.y);
    }
    a0 += __shfl_xor(a0, 32);
    a1 += __shfl_xor(a1, 32);
    a2 += __shfl_xor(a2, 32);
    a3 += __shfl_xor(a3, 32);
    if (half == 0)
        he_feat2[((unsigned)h << 5) + q] = make_uint2(packbf(a0, a1), packbf(a2, a3));
}

// ---------------------------------------------------------------------------
// Stages 3-5 fused: per-node online softmax + weighted accumulate.
// Q bf16; logits in log2 units; raw v_exp_f32; 32-bit gather indices.
// ---------------------------------------------------------------------------
__global__ void fused_attn(const uint2* __restrict__ Qb,
                           const uint2* __restrict__ he_feat2,
                           const int* __restrict__ node_ptr,
                           const int* __restrict__ hes,
                           uint2* __restrict__ node_out_bf, int N)
{
    // 1/sqrt(32) * log2(e): logits in log2 domain; softmax ratios unchanged
    const float SCL = 0.17677669529663687f * 1.4426950408889634f;
    const float NEG = -1e30f;
    int n = blockIdx.x * 4 + (threadIdx.x >> 6);
    if (n >= N) return;
    unsigned lane = threadIdx.x & 63;
    unsigned half = lane >> 5;
    unsigned q    = lane & 31;
    int beg = node_ptr[n], end = node_ptr[n + 1];
    uint2 qu = Qb[((unsigned)n << 5) + q];
    float4 q4;
    q4.x = bflo(qu.x) * SCL; q4.y = bfhi(qu.x) * SCL;
    q4.z = bflo(qu.y) * SCL; q4.w = bfhi(qu.y) * SCL;
    float m = NEG, s = 0.f;
    float a0 = 0.f, a1 = 0.f, a2 = 0.f, a3 = 0.f;

    for (int p = beg; p < end; p += 8) {
        const int last = end - 1;
        int iA = p     + (int)half, iB = p + 2 + (int)half;
        int iC = p + 4 + (int)half, iD = p + 6 + (int)half;
        bool vA = iA <= last, vB = iB <= last, vC = iC <= last, vD = iD <= last;
        unsigned hA = (unsigned)hes[vA ? iA : last];
        unsigned hB = (unsigned)hes[vB ? iB : last];
        unsigned hC = (unsigned)hes[vC ? iC : last];
        unsigned hD = (unsigned)hes[vD ? iD : last];
        uint2 uA = he_feat2[(hA << 5) + q];
        uint2 uB = he_feat2[(hB << 5) + q];
        uint2 uC = he_feat2[(hC << 5) + q];
        uint2 uD = he_feat2[(hD << 5) + q];
        float fA0 = bflo(uA.x), fA1 = bfhi(uA.x), fA2 = bflo(uA.y), fA3 = bfhi(uA.y);
        float fB0 = bflo(uB.x), fB1 = bfhi(uB.x), fB2 = bflo(uB.y), fB3 = bfhi(uB.y);
        float fC0 = bflo(uC.x), fC1 = bfhi(uC.x), fC2 = bflo(uC.y), fC3 = bfhi(uC.y);
        float fD0 = bflo(uD.x), fD1 = bfhi(uD.x), fD2 = bflo(uD.y), fD3 = bfhi(uD.y);
        float dA = q4.x * fA0 + q4.y * fA1 + q4.z * fA2 + q4.w * fA3;
        float dB = q4.x * fB0 + q4.y * fB1 + q4.z * fB2 + q4.w * fB3;
        float dC = q4.x * fC0 + q4.y * fC1 + q4.z * fC2 + q4.w * fC3;
        float dD = q4.x * fD0 + q4.y * fD1 + q4.z * fD2 + q4.w * fD3;
        dA = red8(dA); dB = red8(dB); dC = red8(dC); dD = red8(dD);
        float aA = vA ? dA : NEG;
        float aB = vB ? dB : NEG;
        float aC = vC ? dC : NEG;
        float aD = vD ? dD : NEG;
        float newm = fmaxf(m, fmaxf(fmaxf(aA, aB), fmaxf(aC, aD)));
        float scale = fexp2(m - newm);
        float wA = fexp2(aA - newm), wB = fexp2(aB - newm);
        float wC = fexp2(aC - newm), wD = fexp2(aD - newm);
        s  = s  * scale + ((wA + wB) + (wC + wD));
        a0 = a0 * scale + ((wA * fA0 + wB * fB0) + (wC * fC0 + wD * fD0));
        a1 = a1 * scale + ((wA * fA1 + wB * fB1) + (wC * fC1 + wD * fD1));
        a2 = a2 * scale + ((wA * fA2 + wB * fB2) + (wC * fC2 + wD * fD2));
        a3 = a3 * scale + ((wA * fA3 + wB * fB3) + (wC * fC3 + wD * fD3));
        m = newm;
    }

    float mo = __shfl_xor(m, 32);
    float so = __shfl_xor(s, 32);
    float b0 = __shfl_xor(a0, 32);
    float b1 = __shfl_xor(a1, 32);
    float b2 = __shfl_xor(a2, 32);
    float b3 = __shfl_xor(a3, 32);
    float M  = fmaxf(m, mo);
    float e1 = fexp2(m - M), e2 = fexp2(mo - M);
    float S  = s * e1 + so * e2;
    float inv = 1.f / (S + 1e-16f);
    if (half == 0) {
        float o0 = (a0 * e1 + b0 * e2) * inv;
        float o1 = (a1 * e1 + b1 * e2) * inv;
        float o2 = (a2 * e1 + b2 * e2) * inv;
        float o3 = (a3 * e1 + b3 * e2) * inv;
        node_out_bf[((unsigned)n << 5) + q] = make_uint2(packbf(o0, o1), packbf(o2, o3));
    }
}

// ---------------------------------------------------------------------------
extern "C" void kernel_launch(void* const* d_in, const int* in_sizes, int n_in,
                              void* d_out, int out_size, void* d_ws, size_t ws_size,
                              hipStream_t stream)
{
    const float* x        = (const float*)d_in[0];
    const int*   node_idx = (const int*)d_in[1];
    const int*   he_idx   = (const int*)d_in[2];
    const float* Wk       = (const float*)d_in[3];
    const float* bk       = (const float*)d_in[4];
    const float* Wq       = (const float*)d_in[5];
    const float* bq       = (const float*)d_in[6];
    const float* Wa       = (const float*)d_in[7];
    const float* ba       = (const float*)d_in[8];
    float*       out      = (float*)d_out;

    const int N = in_sizes[0] / D;
    const int E = in_sizes[1];

    const int nblk  = (E + BIN_CH - 1) / BIN_CH;
    const int nb_he = (NUM_HE + 31) >> 5;    // 625 buckets of 32 hyperedges
    const int nb_nd = (N + 127) >> 7;        // 782 buckets of 128 nodes

    // Workspace layout.
    float* ws      = (float*)d_ws;
    float* Kbuf    = ws;                               // N*D region: bf16 K, later bf16 node_out
    float* Qbuf    = Kbuf    + (size_t)N * D;          // N*D region (bf16 Q in half)
    float* he_feat = Qbuf    + (size_t)N * D;          // NUM_HE*D region (bf16 in half)
    unsigned short* wfrag = (unsigned short*)(he_feat + (size_t)NUM_HE * D); // 3*32768
    int*   ibase     = (int*)(wfrag + 3 * 32768);
    int*   he_ptr    = ibase;                            // NUM_HE+1
    int*   nd_ptr    = he_ptr    + (NUM_HE + 1);         // N+1
    int*   he_mem    = nd_ptr    + (N + 1);              // E (node ids by he)
    int*   nd_he     = he_mem    + E;                    // E (he ids by node)
    int*   counts_he = nd_he     + E;                    // nblk*nb_he
    int*   boffs_he  = counts_he + (size_t)nblk * nb_he; // nblk*nb_he
    int*   counts_nd = boffs_he  + (size_t)nblk * nb_he; // nblk*nb_nd
    int*   boffs_nd  = counts_nd + (size_t)nblk * nb_nd; // nblk*nb_nd
    int*   btot      = boffs_nd  + (size_t)nblk * nb_nd; // nb_he+nb_nd
    int*   bbase     = btot      + (nb_he + nb_nd);      // nb_he+nb_nd
    unsigned* staging_he = (unsigned*)(bbase + (nb_he + nb_nd)); // E
    unsigned* staging_nd = staging_he + E;                        // E

    // W fragments (hi/lo) for all three projections
    wprep<<<(3 * 16384 + 255) / 256, 256, 0, stream>>>(Wk, Wq, Wa, wfrag);

    // Stage 1: fused K (bf16, 1-MFMA) + Q (bf16 store, 3-MFMA compute)
    gemm_kq<<<(N + 127) / 128, 256, 0, stream>>>(
        x, wfrag, wfrag + 32768, wfrag + 49152,
        bk, bq, (unsigned short*)Kbuf, (unsigned short*)Qbuf, N);

    // Two-sided binning (one pass over both index arrays)
    stage_both<<<nblk, 256, 0, stream>>>(
        he_idx, node_idx,
        counts_he, boffs_he, staging_he,
        counts_nd, boffs_nd, staging_nd, E, nb_he, nb_nd);
    bucket_tot2<<<(nb_he + nb_nd + 3) / 4, 256, 0, stream>>>(
        counts_he, counts_nd, btot, nb_he, nb_nd, nblk);
    bucket_scan2<<<2, 1024, 0, stream>>>(
        btot, bbase, he_ptr, nd_ptr, NUM_HE, N, nb_he, nb_nd, E);

    // he-side CSR fill + gather
    fill_csr<5><<<nb_he, 256, 0, stream>>>(
        staging_he, counts_he, boffs_he, bbase, he_ptr, he_mem, NUM_HE, nb_he, nblk);
    gather_he<<<(NUM_HE + 3) / 4, 256, 0, stream>>>(
        (const uint2*)Kbuf, he_ptr, he_mem, (uint2*)he_feat, NUM_HE);

    // nd-side CSR fill
    fill_csr<7><<<nb_nd, 256, 0, stream>>>(
        staging_nd, counts_nd, boffs_nd, bbase + nb_he, nd_ptr, nd_he, N, nb_nd, nblk);

    // Stages 3-5: fused attention (bf16 K dead; Kbuf region becomes bf16 node_out)
    fused_attn<<<(N + 3) / 4, 256, 0, stream>>>(
        (const uint2*)Qbuf, (const uint2*)he_feat, nd_ptr, nd_he, (uint2*)Kbuf, N);

    // Stage 6: residual (x fp32) + bf16 node_out @ Wa
    gemm_out<<<(N + 127) / 128, 256, 0, stream>>>(
        (const unsigned short*)Kbuf, x, wfrag + 65536, wfrag + 81920, ba, out, N);
}

// Round 21
// 242.419 us; speedup vs baseline: 1.0448x; 1.0448x over previous
//
#include <hip/hip_runtime.h>
#include <math.h>

#define D 128
#define HEADS 4
#define DK 32
#define NUM_HE 20000
#define BIN_CH 4096

typedef short bf16x8 __attribute__((ext_vector_type(8)));
typedef float f32x4  __attribute__((ext_vector_type(4)));

__device__ __forceinline__ unsigned short f2bf(float f) {
    unsigned int u = __float_as_uint(f);
    u = (u + 0x7fffu + ((u >> 16) & 1u)) >> 16;
    return (unsigned short)u;
}
__device__ __forceinline__ float bf2f(unsigned short h) {
    return __uint_as_float(((unsigned int)h) << 16);
}
__device__ __forceinline__ float bflo(unsigned int u) {
    return __uint_as_float(u << 16);
}
__device__ __forceinline__ float bfhi(unsigned int u) {
    return __uint_as_float(u & 0xffff0000u);
}
__device__ __forceinline__ unsigned int packbf(float lo, float hi) {
    return (unsigned int)f2bf(lo) | ((unsigned int)f2bf(hi) << 16);
}
// raw v_exp_f32: computes 2^x in one VALU instruction (ISA §3)
__device__ __forceinline__ float fexp2(float x) {
    float r;
    asm("v_exp_f32 %0, %1" : "=v"(r) : "v"(x));
    return r;
}
// butterfly add over 8-lane groups via DPP (VALU pipe, no LDS)
template<int CTRL>
__device__ __forceinline__ float dppadd(float v) {
    int s = __builtin_amdgcn_update_dpp(0, __float_as_int(v), CTRL, 0xf, 0xf, true);
    return v + __int_as_float(s);
}
__device__ __forceinline__ float red8(float v) {
    v = dppadd<0xB1>(v);    // quad_perm [1,0,3,2]  (xor 1)
    v = dppadd<0x4E>(v);    // quad_perm [2,3,0,1]  (xor 2)
    v = dppadd<0x141>(v);   // row_half_mirror      (xor 4 equivalent)
    return v;
}

// ---------------------------------------------------------------------------
// W preprocessing: fragment-order Wk|Wq|Wa as bf16 hi/lo.
// ---------------------------------------------------------------------------
__global__ void wprep(const float* __restrict__ Wk, const float* __restrict__ Wq,
                      const float* __restrict__ Wa, unsigned short* __restrict__ dst)
{
    int t = blockIdx.x * blockDim.x + threadIdx.x;
    if (t >= 3 * 16384) return;
    int w = t >> 14, rem = t & 16383;
    int ks = rem >> 12, nf = (rem >> 9) & 7, lane = (rem >> 3) & 63, j = rem & 7;
    int r = ks * 32 + (lane >> 4) * 8 + j;
    int c = nf * 16 + (lane & 15);
    const float* W = (w == 0) ? Wk : (w == 1) ? Wq : Wa;
    float v = W[r * 128 + c];
    unsigned short h = f2bf(v);
    dst[(size_t)w * 32768 + rem]         = h;
    dst[(size_t)w * 32768 + 16384 + rem] = f2bf(v - bf2f(h));
}

// ---------------------------------------------------------------------------
// LDS exclusive scan helper for the binning path.
// ---------------------------------------------------------------------------
__device__ __forceinline__ void lds_exscan(int* hist, int* offs, int* wtot,
                                           int nb, int tid, int lane, int wid)
{
    const int i0 = tid * 4;
    int v0 = (i0 + 0 < nb) ? hist[i0 + 0] : 0;
    int v1 = (i0 + 1 < nb) ? hist[i0 + 1] : 0;
    int v2 = (i0 + 2 < nb) ? hist[i0 + 2] : 0;
    int v3 = (i0 + 3 < nb) ? hist[i0 + 3] : 0;
    int tsum = v0 + v1 + v2 + v3;
    int x = tsum;
    #pragma unroll
    for (int off = 1; off < 64; off <<= 1) {
        int y = __shfl_up(x, off);
        if (lane >= off) x += y;
    }
    if (lane == 63) wtot[wid] = x;
    __syncthreads();
    if (tid == 0) {
        int r = 0;
        #pragma unroll
        for (int w = 0; w < 4; ++w) { int c = wtot[w]; wtot[w] = r; r += c; }
    }
    __syncthreads();
    int base = wtot[wid] + x - tsum;
    if (i0 + 0 < nb) offs[i0 + 0] = base; base += v0;
    if (i0 + 1 < nb) offs[i0 + 1] = base; base += v1;
    if (i0 + 2 < nb) offs[i0 + 2] = base; base += v2;
    if (i0 + 3 < nb) offs[i0 + 3] = base;
    __syncthreads();
}

// ---------------------------------------------------------------------------
// FUSED: K+Q projection blocks  ++  two-sided binning blocks.
// Blocks [0, ggrid) run the MFMA projection (latency/stall-bound, low occ);
// blocks [ggrid, ggrid+nblk) run index binning (streaming) and fill the
// machine under the gemm blocks' stall bubbles. Independent inputs/outputs.
// Shared 32 KB LDS buffer serves both paths.
// ---------------------------------------------------------------------------
__global__ __launch_bounds__(256) void gemm_kq_stage(
    const float* __restrict__ A,
    const unsigned short* __restrict__ BhK,
    const unsigned short* __restrict__ BhQ, const unsigned short* __restrict__ BlQ,
    const float* __restrict__ bk, const float* __restrict__ bq,
    unsigned short* __restrict__ K, unsigned short* __restrict__ Q, int M, int ggrid,
    const int* __restrict__ he_idx, const int* __restrict__ nd_idx,
    int* __restrict__ counts_he, int* __restrict__ boffs_he,
    unsigned* __restrict__ staging_he,
    int* __restrict__ counts_nd, int* __restrict__ boffs_nd,
    unsigned* __restrict__ staging_nd,
    int E, int nb_he, int nb_nd)
{
    __shared__ int smem[8192];   // 32 KB shared by both paths
    const int tid = threadIdx.x;

    if (blockIdx.x < ggrid) {
        // ================= GEMM path (identical math to R18/R19) ==========
        unsigned short (*tile)[32][128] = (unsigned short (*)[32][128])smem;
        const int lane = tid & 63;
        const int wv   = tid >> 6;
        const int r0   = blockIdx.x * 128 + wv * 32;
        const int lr   = lane & 15;
        const int kg   = lane >> 4;
        unsigned short (*mytile)[128] = tile[wv];

        f32x4 ack[2][8], acq[2][8];
        #pragma unroll
        for (int m = 0; m < 2; ++m)
            #pragma unroll
            for (int n = 0; n < 8; ++n) {
                ack[m][n] = (f32x4){0.f, 0.f, 0.f, 0.f};
                acq[m][n] = (f32x4){0.f, 0.f, 0.f, 0.f};
            }

        int row[2];
        row[0] = min(r0 + lr,      M - 1);
        row[1] = min(r0 + 16 + lr, M - 1);

        for (int ks = 0; ks < 4; ++ks) {
            bf16x8 ah[2], al[2];
            #pragma unroll
            for (int m = 0; m < 2; ++m) {
                const float* p = A + (size_t)row[m] * D + ks * 32 + kg * 8;
                float4 v0 = *(const float4*)p;
                float4 v1 = *(const float4*)(p + 4);
                float vv[8] = {v0.x, v0.y, v0.z, v0.w, v1.x, v1.y, v1.z, v1.w};
                #pragma unroll
                for (int j = 0; j < 8; ++j) {
                    unsigned short h = f2bf(vv[j]);
                    ah[m][j] = (short)h;
                    al[m][j] = (short)f2bf(vv[j] - bf2f(h));
                }
            }
            #pragma unroll
            for (int nf = 0; nf < 8; ++nf) {
                const int boff = ((ks * 8 + nf) * 64 + lane) * 8;
                bf16x8 bhk = *(const bf16x8*)(const void*)(BhK + boff);
                bf16x8 bhq = *(const bf16x8*)(const void*)(BhQ + boff);
                bf16x8 blq = *(const bf16x8*)(const void*)(BlQ + boff);
                #pragma unroll
                for (int m = 0; m < 2; ++m) {
                    ack[m][nf] = __builtin_amdgcn_mfma_f32_16x16x32_bf16(ah[m], bhk, ack[m][nf], 0, 0, 0);
                    acq[m][nf] = __builtin_amdgcn_mfma_f32_16x16x32_bf16(ah[m], bhq, acq[m][nf], 0, 0, 0);
                    acq[m][nf] = __builtin_amdgcn_mfma_f32_16x16x32_bf16(ah[m], blq, acq[m][nf], 0, 0, 0);
                    acq[m][nf] = __builtin_amdgcn_mfma_f32_16x16x32_bf16(al[m], bhq, acq[m][nf], 0, 0, 0);
                }
            }
        }

        // K epilogue: stage (swizzled) -> coalesced 256B rows
        #pragma unroll
        for (int nf = 0; nf < 8; ++nf) {
            int col = nf * 16 + lr;
            float bkv = bk[col];
            int colp = col ^ (kg << 4);
            #pragma unroll
            for (int m = 0; m < 2; ++m)
                #pragma unroll
                for (int j = 0; j < 4; ++j)
                    mytile[m * 16 + kg * 4 + j][colp] = f2bf(ack[m][nf][j] + bkv);
        }
        #pragma unroll
        for (int it = 0; it < 8; ++it) {
            int idx  = it * 64 + lane;
            int lrow = idx >> 4;
            int chnk = idx & 15;
            int pch  = chnk ^ (((lrow >> 2) & 3) << 1);
            uint4 v = *(const uint4*)&mytile[lrow][pch * 8];
            int gr = r0 + lrow;
            if (gr < M) *(uint4*)(K + (size_t)gr * D + chnk * 8) = v;
        }

        // Q epilogue (reuse the tile)
        #pragma unroll
        for (int nf = 0; nf < 8; ++nf) {
            int col = nf * 16 + lr;
            float bqv = bq[col];
            int colp = col ^ (kg << 4);
            #pragma unroll
            for (int m = 0; m < 2; ++m)
                #pragma unroll
                for (int j = 0; j < 4; ++j)
                    mytile[m * 16 + kg * 4 + j][colp] = f2bf(acq[m][nf][j] + bqv);
        }
        #pragma unroll
        for (int it = 0; it < 8; ++it) {
            int idx  = it * 64 + lane;
            int lrow = idx >> 4;
            int chnk = idx & 15;
            int pch  = chnk ^ (((lrow >> 2) & 3) << 1);
            uint4 v = *(const uint4*)&mytile[lrow][pch * 8];
            int gr = r0 + lrow;
            if (gr < M) *(uint4*)(Q + (size_t)gr * D + chnk * 8) = v;
        }
    } else {
        // ================= Binning path (identical math to stage_both) ====
        const int bid  = blockIdx.x - ggrid;
        const int lane = tid & 63, wid = tid >> 6;
        const int e0   = bid * BIN_CH;
        int* hist_he = smem;             // 640
        int* offs_he = hist_he + 640;    // 640
        int* hist_nd = offs_he + 640;    // 800
        int* offs_nd = hist_nd + 800;    // 800
        int* wtot    = offs_nd + 800;    // 4

        for (int i = tid; i < nb_he; i += 256) hist_he[i] = 0;
        for (int i = tid; i < nb_nd; i += 256) hist_nd[i] = 0;
        __syncthreads();

        int myhe[16], mynd[16], rhe[16], rnd[16];
        #pragma unroll
        for (int j = 0; j < 16; ++j) {
            int e = e0 + j * 256 + tid;
            if (e < E) {
                int h = he_idx[e], n = nd_idx[e];
                myhe[j] = h; mynd[j] = n;
                rhe[j] = atomicAdd(&hist_he[h >> 5], 1);
                rnd[j] = atomicAdd(&hist_nd[n >> 7], 1);
            } else myhe[j] = -1;
        }
        __syncthreads();

        lds_exscan(hist_he, offs_he, wtot, nb_he, tid, lane, wid);
        lds_exscan(hist_nd, offs_nd, wtot, nb_nd, tid, lane, wid);

        for (int i = tid; i < nb_he; i += 256) {
            counts_he[(size_t)bid * nb_he + i] = hist_he[i];
            boffs_he [(size_t)bid * nb_he + i] = offs_he[i];
        }
        for (int i = tid; i < nb_nd; i += 256) {
            counts_nd[(size_t)bid * nb_nd + i] = hist_nd[i];
            boffs_nd [(size_t)bid * nb_nd + i] = offs_nd[i];
        }
        #pragma unroll
        for (int j = 0; j < 16; ++j) {
            if (myhe[j] >= 0) {
                int bh = myhe[j] >> 5;
                staging_he[e0 + offs_he[bh] + rhe[j]] =
                    ((unsigned)(myhe[j] & 31) << 20) | (unsigned)mynd[j];
                int bn = mynd[j] >> 7;
                staging_nd[e0 + offs_nd[bn] + rnd[j]] =
                    ((unsigned)(mynd[j] & 127) << 20) | (unsigned)myhe[j];
            }
        }
    }
}

// ---------------------------------------------------------------------------
// Output projection: A = bf16 node_out + fp32 residual x; fp32 out.
// ---------------------------------------------------------------------------
__global__ __launch_bounds__(256) void gemm_out(
    const unsigned short* __restrict__ A, const float* __restrict__ R,
    const unsigned short* __restrict__ Bh, const unsigned short* __restrict__ Bl,
    const float* __restrict__ bias, float* __restrict__ C, int M)
{
    const int lane = threadIdx.x & 63;
    const int wv   = threadIdx.x >> 6;
    const int r0   = blockIdx.x * 128 + wv * 32;
    const int lr   = lane & 15;
    const int kg   = lane >> 4;

    f32x4 acc[2][8];
    #pragma unroll
    for (int m = 0; m < 2; ++m)
        #pragma unroll
        for (int n = 0; n < 8; ++n) acc[m][n] = (f32x4){0.f, 0.f, 0.f, 0.f};

    int row[2];
    row[0] = min(r0 + lr,      M - 1);
    row[1] = min(r0 + 16 + lr, M - 1);

    for (int ks = 0; ks < 4; ++ks) {
        bf16x8 ah[2], al[2];
        #pragma unroll
        for (int m = 0; m < 2; ++m) {
            const unsigned short* pa = A + (size_t)row[m] * D + ks * 32 + kg * 8;
            uint4 av = *(const uint4*)(const void*)pa;
            const float* q = R + (size_t)row[m] * D + ks * 32 + kg * 8;
            float4 u0 = *(const float4*)q;
            float4 u1 = *(const float4*)(q + 4);
            float vv[8];
            vv[0] = bflo(av.x) + u0.x; vv[1] = bfhi(av.x) + u0.y;
            vv[2] = bflo(av.y) + u0.z; vv[3] = bfhi(av.y) + u0.w;
            vv[4] = bflo(av.z) + u1.x; vv[5] = bfhi(av.z) + u1.y;
            vv[6] = bflo(av.w) + u1.z; vv[7] = bfhi(av.w) + u1.w;
            #pragma unroll
            for (int j = 0; j < 8; ++j) {
                unsigned short h = f2bf(vv[j]);
                ah[m][j] = (short)h;
                al[m][j] = (short)f2bf(vv[j] - bf2f(h));
            }
        }
        #pragma unroll
        for (int nf = 0; nf < 8; ++nf) {
            const int boff = ((ks * 8 + nf) * 64 + lane) * 8;
            bf16x8 bh = *(const bf16x8*)(const void*)(Bh + boff);
            bf16x8 bl = *(const bf16x8*)(const void*)(Bl + boff);
            #pragma unroll
            for (int m = 0; m < 2; ++m) {
                acc[m][nf] = __builtin_amdgcn_mfma_f32_16x16x32_bf16(ah[m], bh, acc[m][nf], 0, 0, 0);
                acc[m][nf] = __builtin_amdgcn_mfma_f32_16x16x32_bf16(ah[m], bl, acc[m][nf], 0, 0, 0);
                acc[m][nf] = __builtin_amdgcn_mfma_f32_16x16x32_bf16(al[m], bh, acc[m][nf], 0, 0, 0);
            }
        }
    }

    #pragma unroll
    for (int nf = 0; nf < 8; ++nf) {
        int col = nf * 16 + lr;
        float bv = bias[col];
        #pragma unroll
        for (int m = 0; m < 2; ++m) {
            #pragma unroll
            for (int j = 0; j < 4; ++j) {
                int gr = r0 + m * 16 + kg * 4 + j;
                if (gr < M) C[(size_t)gr * D + col] = acc[m][nf][j] + bv;
            }
        }
    }
}

__global__ void bucket_tot2(const int* __restrict__ counts_he,
                            const int* __restrict__ counts_nd,
                            int* __restrict__ btot, int nb_he, int nb_nd, int nblk)
{
    int k = blockIdx.x * 4 + (threadIdx.x >> 6);
    if (k >= nb_he + nb_nd) return;
    int lane = threadIdx.x & 63;
    const int* counts = (k < nb_he) ? counts_he : counts_nd;
    int nb = (k < nb_he) ? nb_he : nb_nd;
    int kk = (k < nb_he) ? k : k - nb_he;
    int s = 0;
    for (int b = lane; b < nblk; b += 64) s += counts[(size_t)b * nb + kk];
    #pragma unroll
    for (int off = 1; off < 64; off <<= 1) s += __shfl_xor(s, off);
    if (lane == 0) btot[k] = s;
}

__global__ void bucket_scan2(const int* __restrict__ btot, int* __restrict__ bbase,
                             int* __restrict__ he_ptr, int* __restrict__ nd_ptr,
                             int nseg_he, int nseg_nd, int nb_he, int nb_nd, int Etot)
{
    __shared__ int wsum[16];
    const int side = blockIdx.x;
    const int nb   = side ? nb_nd : nb_he;
    const int off0 = side ? nb_he : 0;
    int* ptr       = side ? nd_ptr : he_ptr;
    const int nseg = side ? nseg_nd : nseg_he;
    const int tid = threadIdx.x, lane = tid & 63, wid = tid >> 6;
    int v = (tid < nb) ? btot[off0 + tid] : 0;
    int x = v;
    #pragma unroll
    for (int off = 1; off < 64; off <<= 1) {
        int y = __shfl_up(x, off);
        if (lane >= off) x += y;
    }
    if (lane == 63) wsum[wid] = x;
    __syncthreads();
    if (wid == 0) {
        int wv = (lane < 16) ? wsum[lane] : 0;
        #pragma unroll
        for (int off = 1; off < 16; off <<= 1) {
            int y = __shfl_up(wv, off);
            if (lane >= off) wv += y;
        }
        if (lane < 16) wsum[lane] = wv;
    }
    __syncthreads();
    int base = (wid > 0) ? wsum[wid - 1] : 0;
    if (tid < nb) bbase[off0 + tid] = base + x - v;
    if (tid == 0) ptr[nseg] = Etot;
}

template<int SHIFT>
__global__ __launch_bounds__(256) void fill_csr(
    const unsigned* __restrict__ staging, const int* __restrict__ counts,
    const int* __restrict__ boffs, const int* __restrict__ bbase,
    int* __restrict__ ptr, int* __restrict__ outv,
    int nseg, int nb, int nblk)
{
    __shared__ int cur[1 << SHIFT];
    const int tid = threadIdx.x;
    const int k   = blockIdx.x;
    const int s0  = k << SHIFT;
    const int NS  = min(1 << SHIFT, nseg - s0);
    for (int i = tid; i < NS; i += 256) cur[i] = 0;
    __syncthreads();
    for (int b = tid; b < nblk; b += 256) {
        int c   = counts[(size_t)b * nb + k];
        int off = b * BIN_CH + boffs[(size_t)b * nb + k];
        for (int i = 0; i < c; ++i) {
            int sl = (int)(staging[off + i] >> 20);
            atomicAdd(&cur[sl], 1);
        }
    }
    __syncthreads();
    if (tid == 0) {
        int run = bbase[k];
        for (int i = 0; i < NS; ++i) {
            int c = cur[i];
            cur[i] = run;
            ptr[s0 + i] = run;
            run += c;
        }
    }
    __syncthreads();
    for (int b = tid; b < nblk; b += 256) {
        int c   = counts[(size_t)b * nb + k];
        int off = b * BIN_CH + boffs[(size_t)b * nb + k];
        for (int i = 0; i < c; ++i) {
            unsigned pv = staging[off + i];
            int pos = atomicAdd(&cur[pv >> 20], 1);
            outv[pos] = (int)(pv & 0xFFFFFu);
        }
    }
}

// ---------------------------------------------------------------------------
// Stage 2: he_feat[h] = sum of member K rows (half-wave layout, CSR gather).
// ---------------------------------------------------------------------------
__global__ void gather_he(const uint2* __restrict__ K2,
                          const int* __restrict__ he_ptr,
                          const int* __restrict__ members,
                          uint2* __restrict__ he_feat2, int HE)
{
    int h = blockIdx.x * 4 + (threadIdx.x >> 6);
    if (h >= HE) return;
    unsigned lane = threadIdx.x & 63;
    unsigned half = lane >> 5;
    unsigned q    = lane & 31;
    int beg = he_ptr[h], end = he_ptr[h + 1];
    float a0 = 0.f, a1 = 0.f, a2 = 0.f, a3 = 0.f;
    int p = beg;
    for (; p + 7 < end; p += 8) {
        unsigned nA = (unsigned)members[p     + half];
        unsigned nB = (unsigned)members[p + 2 + half];
        unsigned nC = (unsigned)members[p + 4 + half];
        unsigned nD = (unsigned)members[p + 6 + half];
        uint2 uA = K2[(nA << 5) + q];
        uint2 uB = K2[(nB << 5) + q];
        uint2 uC = K2[(nC << 5) + q];
        uint2 uD = K2[(nD << 5) + q];
        a0 += (bflo(uA.x) + bflo(uB.x)) + (bflo(uC.x) + bflo(uD.x));
        a1 += (bfhi(uA.x) + bfhi(uB.x)) + (bfhi(uC.x) + bfhi(uD.x));
        a2 += (bflo(uA.y) + bflo(uB.y)) + (bflo(uC.y) + bflo(uD.y));
        a3 += (bfhi(uA.y) + bfhi(uB.y)) + (bfhi(uC.y) + bfhi(uD.y));
    }
    for (; p < end; p += 2) {
        int pi = p + (int)half;
        bool valid = pi < end;
        unsigned nn = (unsigned)members[valid ? pi : beg];
        uint2 u = K2[(nn << 5) + q];
        float w = valid ? 1.f : 0.f;
        a0 += w * bflo(u.x);
        a1 += w * bfhi(u.x);
        a2 += w * bflo(u.y);
        a3 += w * bfhi(u.y);
    }
    a0 += __shfl_xor(a0, 32);
    a1 += __shfl_xor(a1, 32);
    a2 += __shfl_xor(a2, 32);
    a3 += __shfl_xor(a3, 32);
    if (half == 0)
        he_feat2[((unsigned)h << 5) + q] = make_uint2(packbf(a0, a1), packbf(a2, a3));
}

// ---------------------------------------------------------------------------
// Stages 3-5 fused: per-node online softmax + weighted accumulate.
// Q bf16; logits in log2 units; raw v_exp_f32; 32-bit gather indices.
// ---------------------------------------------------------------------------
__global__ void fused_attn(const uint2* __restrict__ Qb,
                           const uint2* __restrict__ he_feat2,
                           const int* __restrict__ node_ptr,
                           const int* __restrict__ hes,
                           uint2* __restrict__ node_out_bf, int N)
{
    const float SCL = 0.17677669529663687f * 1.4426950408889634f;
    const float NEG = -1e30f;
    int n = blockIdx.x * 4 + (threadIdx.x >> 6);
    if (n >= N) return;
    unsigned lane = threadIdx.x & 63;
    unsigned half = lane >> 5;
    unsigned q    = lane & 31;
    int beg = node_ptr[n], end = node_ptr[n + 1];
    uint2 qu = Qb[((unsigned)n << 5) + q];
    float4 q4;
    q4.x = bflo(qu.x) * SCL; q4.y = bfhi(qu.x) * SCL;
    q4.z = bflo(qu.y) * SCL; q4.w = bfhi(qu.y) * SCL;
    float m = NEG, s = 0.f;
    float a0 = 0.f, a1 = 0.f, a2 = 0.f, a3 = 0.f;

    for (int p = beg; p < end; p += 8) {
        const int last = end - 1;
        int iA = p     + (int)half, iB = p + 2 + (int)half;
        int iC = p + 4 + (int)half, iD = p + 6 + (int)half;
        bool vA = iA <= last, vB = iB <= last, vC = iC <= last, vD = iD <= last;
        unsigned hA = (unsigned)hes[vA ? iA : last];
        unsigned hB = (unsigned)hes[vB ? iB : last];
        unsigned hC = (unsigned)hes[vC ? iC : last];
        unsigned hD = (unsigned)hes[vD ? iD : last];
        uint2 uA = he_feat2[(hA << 5) + q];
        uint2 uB = he_feat2[(hB << 5) + q];
        uint2 uC = he_feat2[(hC << 5) + q];
        uint2 uD = he_feat2[(hD << 5) + q];
        float fA0 = bflo(uA.x), fA1 = bfhi(uA.x), fA2 = bflo(uA.y), fA3 = bfhi(uA.y);
        float fB0 = bflo(uB.x), fB1 = bfhi(uB.x), fB2 = bflo(uB.y), fB3 = bfhi(uB.y);
        float fC0 = bflo(uC.x), fC1 = bfhi(uC.x), fC2 = bflo(uC.y), fC3 = bfhi(uC.y);
        float fD0 = bflo(uD.x), fD1 = bfhi(uD.x), fD2 = bflo(uD.y), fD3 = bfhi(uD.y);
        float dA = q4.x * fA0 + q4.y * fA1 + q4.z * fA2 + q4.w * fA3;
        float dB = q4.x * fB0 + q4.y * fB1 + q4.z * fB2 + q4.w * fB3;
        float dC = q4.x * fC0 + q4.y * fC1 + q4.z * fC2 + q4.w * fC3;
        float dD = q4.x * fD0 + q4.y * fD1 + q4.z * fD2 + q4.w * fD3;
        dA = red8(dA); dB = red8(dB); dC = red8(dC); dD = red8(dD);
        float aA = vA ? dA : NEG;
        float aB = vB ? dB : NEG;
        float aC = vC ? dC : NEG;
        float aD = vD ? dD : NEG;
        float newm = fmaxf(m, fmaxf(fmaxf(aA, aB), fmaxf(aC, aD)));
        float scale = fexp2(m - newm);
        float wA = fexp2(aA - newm), wB = fexp2(aB - newm);
        float wC = fexp2(aC - newm), wD = fexp2(aD - newm);
        s  = s  * scale + ((wA + wB) + (wC + wD));
        a0 = a0 * scale + ((wA * fA0 + wB * fB0) + (wC * fC0 + wD * fD0));
        a1 = a1 * scale + ((wA * fA1 + wB * fB1) + (wC * fC1 + wD * fD1));
        a2 = a2 * scale + ((wA * fA2 + wB * fB2) + (wC * fC2 + wD * fD2));
        a3 = a3 * scale + ((wA * fA3 + wB * fB3) + (wC * fC3 + wD * fD3));
        m = newm;
    }

    float mo = __shfl_xor(m, 32);
    float so = __shfl_xor(s, 32);
    float b0 = __shfl_xor(a0, 32);
    float b1 = __shfl_xor(a1, 32);
    float b2 = __shfl_xor(a2, 32);
    float b3 = __shfl_xor(a3, 32);
    float M  = fmaxf(m, mo);
    float e1 = fexp2(m - M), e2 = fexp2(mo - M);
    float S  = s * e1 + so * e2;
    float inv = 1.f / (S + 1e-16f);
    if (half == 0) {
        float o0 = (a0 * e1 + b0 * e2) * inv;
        float o1 = (a1 * e1 + b1 * e2) * inv;
        float o2 = (a2 * e1 + b2 * e2) * inv;
        float o3 = (a3 * e1 + b3 * e2) * inv;
        node_out_bf[((unsigned)n << 5) + q] = make_uint2(packbf(o0, o1), packbf(o2, o3));
    }
}

// ---------------------------------------------------------------------------
extern "C" void kernel_launch(void* const* d_in, const int* in_sizes, int n_in,
                              void* d_out, int out_size, void* d_ws, size_t ws_size,
                              hipStream_t stream)
{
    const float* x        = (const float*)d_in[0];
    const int*   node_idx = (const int*)d_in[1];
    const int*   he_idx   = (const int*)d_in[2];
    const float* Wk       = (const float*)d_in[3];
    const float* bk       = (const float*)d_in[4];
    const float* Wq       = (const float*)d_in[5];
    const float* bq       = (const float*)d_in[6];
    const float* Wa       = (const float*)d_in[7];
    const float* ba       = (const float*)d_in[8];
    float*       out      = (float*)d_out;

    const int N = in_sizes[0] / D;
    const int E = in_sizes[1];

    const int nblk  = (E + BIN_CH - 1) / BIN_CH;
    const int nb_he = (NUM_HE + 31) >> 5;    // 625 buckets of 32 hyperedges
    const int nb_nd = (N + 127) >> 7;        // 782 buckets of 128 nodes
    const int ggrid = (N + 127) / 128;

    // Workspace layout.
    float* ws      = (float*)d_ws;
    float* Kbuf    = ws;                               // N*D region: bf16 K, later bf16 node_out
    float* Qbuf    = Kbuf    + (size_t)N * D;          // N*D region (bf16 Q in half)
    float* he_feat = Qbuf    + (size_t)N * D;          // NUM_HE*D region (bf16 in half)
    unsigned short* wfrag = (unsigned short*)(he_feat + (size_t)NUM_HE * D); // 3*32768
    int*   ibase     = (int*)(wfrag + 3 * 32768);
    int*   he_ptr    = ibase;                            // NUM_HE+1
    int*   nd_ptr    = he_ptr    + (NUM_HE + 1);         // N+1
    int*   he_mem    = nd_ptr    + (N + 1);              // E (node ids by he)
    int*   nd_he     = he_mem    + E;                    // E (he ids by node)
    int*   counts_he = nd_he     + E;                    // nblk*nb_he
    int*   boffs_he  = counts_he + (size_t)nblk * nb_he; // nblk*nb_he
    int*   counts_nd = boffs_he  + (size_t)nblk * nb_he; // nblk*nb_nd
    int*   boffs_nd  = counts_nd + (size_t)nblk * nb_nd; // nblk*nb_nd
    int*   btot      = boffs_nd  + (size_t)nblk * nb_nd; // nb_he+nb_nd
    int*   bbase     = btot      + (nb_he + nb_nd);      // nb_he+nb_nd
    unsigned* staging_he = (unsigned*)(bbase + (nb_he + nb_nd)); // E
    unsigned* staging_nd = staging_he + E;                        // E

    // W fragments (hi/lo) for all three projections
    wprep<<<(3 * 16384 + 255) / 256, 256, 0, stream>>>(Wk, Wq, Wa, wfrag);

    // Stage 1 + binning fused: gemm blocks ++ binning blocks (independent)
    gemm_kq_stage<<<ggrid + nblk, 256, 0, stream>>>(
        x, wfrag, wfrag + 32768, wfrag + 49152,
        bk, bq, (unsigned short*)Kbuf, (unsigned short*)Qbuf, N, ggrid,
        he_idx, node_idx,
        counts_he, boffs_he, staging_he,
        counts_nd, boffs_nd, staging_nd, E, nb_he, nb_nd);

    bucket_tot2<<<(nb_he + nb_nd + 3) / 4, 256, 0, stream>>>(
        counts_he, counts_nd, btot, nb_he, nb_nd, nblk);
    bucket_scan2<<<2, 1024, 0, stream>>>(
        btot, bbase, he_ptr, nd_ptr, NUM_HE, N, nb_he, nb_nd, E);

    // he-side CSR fill + gather
    fill_csr<5><<<nb_he, 256, 0, stream>>>(
        staging_he, counts_he, boffs_he, bbase, he_ptr, he_mem, NUM_HE, nb_he, nblk);
    gather_he<<<(NUM_HE + 3) / 4, 256, 0, stream>>>(
        (const uint2*)Kbuf, he_ptr, he_mem, (uint2*)he_feat, NUM_HE);

    // nd-side CSR fill
    fill_csr<7><<<nb_nd, 256, 0, stream>>>(
        staging_nd, counts_nd, boffs_nd, bbase + nb_he, nd_ptr, nd_he, N, nb_nd, nblk);

    // Stages 3-5: fused attention (bf16 K dead; Kbuf region becomes bf16 node_out)
    fused_attn<<<(N + 3) / 4, 256, 0, stream>>>(
        (const uint2*)Qbuf, (const uint2*)he_feat, nd_ptr, nd_he, (uint2*)Kbuf, N);

    // Stage 6: residual (x fp32) + bf16 node_out @ Wa
    gemm_out<<<(N + 127) / 128, 256, 0, stream>>>(
        (const unsigned short*)Kbuf, x, wfrag + 65536, wfrag + 81920, ba, out, N);
}

// Round 22
// 237.745 us; speedup vs baseline: 1.0653x; 1.0197x over previous
//
#include <hip/hip_runtime.h>
#include <math.h>

#define D 128
#define HEADS 4
#define DK 32
#define NUM_HE 20000
#define BIN_CH 4096

typedef short bf16x8 __attribute__((ext_vector_type(8)));
typedef float f32x4  __attribute__((ext_vector_type(4)));

__device__ __forceinline__ unsigned short f2bf(float f) {
    unsigned int u = __float_as_uint(f);
    u = (u + 0x7fffu + ((u >> 16) & 1u)) >> 16;
    return (unsigned short)u;
}
__device__ __forceinline__ float bf2f(unsigned short h) {
    return __uint_as_float(((unsigned int)h) << 16);
}
__device__ __forceinline__ float bflo(unsigned int u) {
    return __uint_as_float(u << 16);
}
__device__ __forceinline__ float bfhi(unsigned int u) {
    return __uint_as_float(u & 0xffff0000u);
}
__device__ __forceinline__ unsigned int packbf(float lo, float hi) {
    return (unsigned int)f2bf(lo) | ((unsigned int)f2bf(hi) << 16);
}
// raw v_exp_f32: computes 2^x in one VALU instruction (ISA §3)
__device__ __forceinline__ float fexp2(float x) {
    float r;
    asm("v_exp_f32 %0, %1" : "=v"(r) : "v"(x));
    return r;
}
// butterfly add over 8-lane groups via DPP (VALU pipe, no LDS)
template<int CTRL>
__device__ __forceinline__ float dppadd(float v) {
    int s = __builtin_amdgcn_update_dpp(0, __float_as_int(v), CTRL, 0xf, 0xf, true);
    return v + __int_as_float(s);
}
__device__ __forceinline__ float red8(float v) {
    v = dppadd<0xB1>(v);    // quad_perm [1,0,3,2]  (xor 1)
    v = dppadd<0x4E>(v);    // quad_perm [2,3,0,1]  (xor 2)
    v = dppadd<0x141>(v);   // row_half_mirror      (xor 4 equivalent)
    return v;
}

// ---------------------------------------------------------------------------
// W preprocessing: fragment-order Wk|Wq|Wa as bf16 hi/lo.
// ---------------------------------------------------------------------------
__global__ void wprep(const float* __restrict__ Wk, const float* __restrict__ Wq,
                      const float* __restrict__ Wa, unsigned short* __restrict__ dst)
{
    int t = blockIdx.x * blockDim.x + threadIdx.x;
    if (t >= 3 * 16384) return;
    int w = t >> 14, rem = t & 16383;
    int ks = rem >> 12, nf = (rem >> 9) & 7, lane = (rem >> 3) & 63, j = rem & 7;
    int r = ks * 32 + (lane >> 4) * 8 + j;
    int c = nf * 16 + (lane & 15);
    const float* W = (w == 0) ? Wk : (w == 1) ? Wq : Wa;
    float v = W[r * 128 + c];
    unsigned short h = f2bf(v);
    dst[(size_t)w * 32768 + rem]         = h;
    dst[(size_t)w * 32768 + 16384 + rem] = f2bf(v - bf2f(h));
}

// ---------------------------------------------------------------------------
// LDS exclusive scan helper for the binning path.
// ---------------------------------------------------------------------------
__device__ __forceinline__ void lds_exscan(int* hist, int* offs, int* wtot,
                                           int nb, int tid, int lane, int wid)
{
    const int i0 = tid * 4;
    int v0 = (i0 + 0 < nb) ? hist[i0 + 0] : 0;
    int v1 = (i0 + 1 < nb) ? hist[i0 + 1] : 0;
    int v2 = (i0 + 2 < nb) ? hist[i0 + 2] : 0;
    int v3 = (i0 + 3 < nb) ? hist[i0 + 3] : 0;
    int tsum = v0 + v1 + v2 + v3;
    int x = tsum;
    #pragma unroll
    for (int off = 1; off < 64; off <<= 1) {
        int y = __shfl_up(x, off);
        if (lane >= off) x += y;
    }
    if (lane == 63) wtot[wid] = x;
    __syncthreads();
    if (tid == 0) {
        int r = 0;
        #pragma unroll
        for (int w = 0; w < 4; ++w) { int c = wtot[w]; wtot[w] = r; r += c; }
    }
    __syncthreads();
    int base = wtot[wid] + x - tsum;
    if (i0 + 0 < nb) offs[i0 + 0] = base; base += v0;
    if (i0 + 1 < nb) offs[i0 + 1] = base; base += v1;
    if (i0 + 2 < nb) offs[i0 + 2] = base; base += v2;
    if (i0 + 3 < nb) offs[i0 + 3] = base;
    __syncthreads();
}

// ---------------------------------------------------------------------------
// FUSED: K+Q projection blocks ++ two-sided binning blocks (R20 winner).
// ---------------------------------------------------------------------------
__global__ __launch_bounds__(256) void gemm_kq_stage(
    const float* __restrict__ A,
    const unsigned short* __restrict__ BhK,
    const unsigned short* __restrict__ BhQ, const unsigned short* __restrict__ BlQ,
    const float* __restrict__ bk, const float* __restrict__ bq,
    unsigned short* __restrict__ K, unsigned short* __restrict__ Q, int M, int ggrid,
    const int* __restrict__ he_idx, const int* __restrict__ nd_idx,
    int* __restrict__ counts_he, int* __restrict__ boffs_he,
    unsigned* __restrict__ staging_he,
    int* __restrict__ counts_nd, int* __restrict__ boffs_nd,
    unsigned* __restrict__ staging_nd,
    int E, int nb_he, int nb_nd)
{
    __shared__ int smem[8192];   // 32 KB shared by both paths
    const int tid = threadIdx.x;

    if (blockIdx.x < ggrid) {
        // ================= GEMM path ==========
        unsigned short (*tile)[32][128] = (unsigned short (*)[32][128])smem;
        const int lane = tid & 63;
        const int wv   = tid >> 6;
        const int r0   = blockIdx.x * 128 + wv * 32;
        const int lr   = lane & 15;
        const int kg   = lane >> 4;
        unsigned short (*mytile)[128] = tile[wv];

        f32x4 ack[2][8], acq[2][8];
        #pragma unroll
        for (int m = 0; m < 2; ++m)
            #pragma unroll
            for (int n = 0; n < 8; ++n) {
                ack[m][n] = (f32x4){0.f, 0.f, 0.f, 0.f};
                acq[m][n] = (f32x4){0.f, 0.f, 0.f, 0.f};
            }

        int row[2];
        row[0] = min(r0 + lr,      M - 1);
        row[1] = min(r0 + 16 + lr, M - 1);

        for (int ks = 0; ks < 4; ++ks) {
            bf16x8 ah[2], al[2];
            #pragma unroll
            for (int m = 0; m < 2; ++m) {
                const float* p = A + (size_t)row[m] * D + ks * 32 + kg * 8;
                float4 v0 = *(const float4*)p;
                float4 v1 = *(const float4*)(p + 4);
                float vv[8] = {v0.x, v0.y, v0.z, v0.w, v1.x, v1.y, v1.z, v1.w};
                #pragma unroll
                for (int j = 0; j < 8; ++j) {
                    unsigned short h = f2bf(vv[j]);
                    ah[m][j] = (short)h;
                    al[m][j] = (short)f2bf(vv[j] - bf2f(h));
                }
            }
            #pragma unroll
            for (int nf = 0; nf < 8; ++nf) {
                const int boff = ((ks * 8 + nf) * 64 + lane) * 8;
                bf16x8 bhk = *(const bf16x8*)(const void*)(BhK + boff);
                bf16x8 bhq = *(const bf16x8*)(const void*)(BhQ + boff);
                bf16x8 blq = *(const bf16x8*)(const void*)(BlQ + boff);
                #pragma unroll
                for (int m = 0; m < 2; ++m) {
                    ack[m][nf] = __builtin_amdgcn_mfma_f32_16x16x32_bf16(ah[m], bhk, ack[m][nf], 0, 0, 0);
                    acq[m][nf] = __builtin_amdgcn_mfma_f32_16x16x32_bf16(ah[m], bhq, acq[m][nf], 0, 0, 0);
                    acq[m][nf] = __builtin_amdgcn_mfma_f32_16x16x32_bf16(ah[m], blq, acq[m][nf], 0, 0, 0);
                    acq[m][nf] = __builtin_amdgcn_mfma_f32_16x16x32_bf16(al[m], bhq, acq[m][nf], 0, 0, 0);
                }
            }
        }

        // K epilogue: stage (swizzled) -> coalesced 256B rows
        #pragma unroll
        for (int nf = 0; nf < 8; ++nf) {
            int col = nf * 16 + lr;
            float bkv = bk[col];
            int colp = col ^ (kg << 4);
            #pragma unroll
            for (int m = 0; m < 2; ++m)
                #pragma unroll
                for (int j = 0; j < 4; ++j)
                    mytile[m * 16 + kg * 4 + j][colp] = f2bf(ack[m][nf][j] + bkv);
        }
        #pragma unroll
        for (int it = 0; it < 8; ++it) {
            int idx  = it * 64 + lane;
            int lrow = idx >> 4;
            int chnk = idx & 15;
            int pch  = chnk ^ (((lrow >> 2) & 3) << 1);
            uint4 v = *(const uint4*)&mytile[lrow][pch * 8];
            int gr = r0 + lrow;
            if (gr < M) *(uint4*)(K + (size_t)gr * D + chnk * 8) = v;
        }

        // Q epilogue (reuse the tile)
        #pragma unroll
        for (int nf = 0; nf < 8; ++nf) {
            int col = nf * 16 + lr;
            float bqv = bq[col];
            int colp = col ^ (kg << 4);
            #pragma unroll
            for (int m = 0; m < 2; ++m)
                #pragma unroll
                for (int j = 0; j < 4; ++j)
                    mytile[m * 16 + kg * 4 + j][colp] = f2bf(acq[m][nf][j] + bqv);
        }
        #pragma unroll
        for (int it = 0; it < 8; ++it) {
            int idx  = it * 64 + lane;
            int lrow = idx >> 4;
            int chnk = idx & 15;
            int pch  = chnk ^ (((lrow >> 2) & 3) << 1);
            uint4 v = *(const uint4*)&mytile[lrow][pch * 8];
            int gr = r0 + lrow;
            if (gr < M) *(uint4*)(Q + (size_t)gr * D + chnk * 8) = v;
        }
    } else {
        // ================= Binning path ====
        const int bid  = blockIdx.x - ggrid;
        const int lane = tid & 63, wid = tid >> 6;
        const int e0   = bid * BIN_CH;
        int* hist_he = smem;             // 640
        int* offs_he = hist_he + 640;    // 640
        int* hist_nd = offs_he + 640;    // 800
        int* offs_nd = hist_nd + 800;    // 800
        int* wtot    = offs_nd + 800;    // 4

        for (int i = tid; i < nb_he; i += 256) hist_he[i] = 0;
        for (int i = tid; i < nb_nd; i += 256) hist_nd[i] = 0;
        __syncthreads();

        int myhe[16], mynd[16], rhe[16], rnd[16];
        #pragma unroll
        for (int j = 0; j < 16; ++j) {
            int e = e0 + j * 256 + tid;
            if (e < E) {
                int h = he_idx[e], n = nd_idx[e];
                myhe[j] = h; mynd[j] = n;
                rhe[j] = atomicAdd(&hist_he[h >> 5], 1);
                rnd[j] = atomicAdd(&hist_nd[n >> 7], 1);
            } else myhe[j] = -1;
        }
        __syncthreads();

        lds_exscan(hist_he, offs_he, wtot, nb_he, tid, lane, wid);
        lds_exscan(hist_nd, offs_nd, wtot, nb_nd, tid, lane, wid);

        for (int i = tid; i < nb_he; i += 256) {
            counts_he[(size_t)bid * nb_he + i] = hist_he[i];
            boffs_he [(size_t)bid * nb_he + i] = offs_he[i];
        }
        for (int i = tid; i < nb_nd; i += 256) {
            counts_nd[(size_t)bid * nb_nd + i] = hist_nd[i];
            boffs_nd [(size_t)bid * nb_nd + i] = offs_nd[i];
        }
        #pragma unroll
        for (int j = 0; j < 16; ++j) {
            if (myhe[j] >= 0) {
                int bh = myhe[j] >> 5;
                staging_he[e0 + offs_he[bh] + rhe[j]] =
                    ((unsigned)(myhe[j] & 31) << 20) | (unsigned)mynd[j];
                int bn = mynd[j] >> 7;
                staging_nd[e0 + offs_nd[bn] + rnd[j]] =
                    ((unsigned)(mynd[j] & 127) << 20) | (unsigned)myhe[j];
            }
        }
    }
}

// ---------------------------------------------------------------------------
// Output projection: A = bf16 node_out + fp32 residual x; fp32 out.
// ---------------------------------------------------------------------------
__global__ __launch_bounds__(256) void gemm_out(
    const unsigned short* __restrict__ A, const float* __restrict__ R,
    const unsigned short* __restrict__ Bh, const unsigned short* __restrict__ Bl,
    const float* __restrict__ bias, float* __restrict__ C, int M)
{
    const int lane = threadIdx.x & 63;
    const int wv   = threadIdx.x >> 6;
    const int r0   = blockIdx.x * 128 + wv * 32;
    const int lr   = lane & 15;
    const int kg   = lane >> 4;

    f32x4 acc[2][8];
    #pragma unroll
    for (int m = 0; m < 2; ++m)
        #pragma unroll
        for (int n = 0; n < 8; ++n) acc[m][n] = (f32x4){0.f, 0.f, 0.f, 0.f};

    int row[2];
    row[0] = min(r0 + lr,      M - 1);
    row[1] = min(r0 + 16 + lr, M - 1);

    for (int ks = 0; ks < 4; ++ks) {
        bf16x8 ah[2], al[2];
        #pragma unroll
        for (int m = 0; m < 2; ++m) {
            const unsigned short* pa = A + (size_t)row[m] * D + ks * 32 + kg * 8;
            uint4 av = *(const uint4*)(const void*)pa;
            const float* q = R + (size_t)row[m] * D + ks * 32 + kg * 8;
            float4 u0 = *(const float4*)q;
            float4 u1 = *(const float4*)(q + 4);
            float vv[8];
            vv[0] = bflo(av.x) + u0.x; vv[1] = bfhi(av.x) + u0.y;
            vv[2] = bflo(av.y) + u0.z; vv[3] = bfhi(av.y) + u0.w;
            vv[4] = bflo(av.z) + u1.x; vv[5] = bfhi(av.z) + u1.y;
            vv[6] = bflo(av.w) + u1.z; vv[7] = bfhi(av.w) + u1.w;
            #pragma unroll
            for (int j = 0; j < 8; ++j) {
                unsigned short h = f2bf(vv[j]);
                ah[m][j] = (short)h;
                al[m][j] = (short)f2bf(vv[j] - bf2f(h));
            }
        }
        #pragma unroll
        for (int nf = 0; nf < 8; ++nf) {
            const int boff = ((ks * 8 + nf) * 64 + lane) * 8;
            bf16x8 bh = *(const bf16x8*)(const void*)(Bh + boff);
            bf16x8 bl = *(const bf16x8*)(const void*)(Bl + boff);
            #pragma unroll
            for (int m = 0; m < 2; ++m) {
                acc[m][nf] = __builtin_amdgcn_mfma_f32_16x16x32_bf16(ah[m], bh, acc[m][nf], 0, 0, 0);
                acc[m][nf] = __builtin_amdgcn_mfma_f32_16x16x32_bf16(ah[m], bl, acc[m][nf], 0, 0, 0);
                acc[m][nf] = __builtin_amdgcn_mfma_f32_16x16x32_bf16(al[m], bh, acc[m][nf], 0, 0, 0);
            }
        }
    }

    #pragma unroll
    for (int nf = 0; nf < 8; ++nf) {
        int col = nf * 16 + lr;
        float bv = bias[col];
        #pragma unroll
        for (int m = 0; m < 2; ++m) {
            #pragma unroll
            for (int j = 0; j < 4; ++j) {
                int gr = r0 + m * 16 + kg * 4 + j;
                if (gr < M) C[(size_t)gr * D + col] = acc[m][nf][j] + bv;
            }
        }
    }
}

__global__ void bucket_tot2(const int* __restrict__ counts_he,
                            const int* __restrict__ counts_nd,
                            int* __restrict__ btot, int nb_he, int nb_nd, int nblk)
{
    int k = blockIdx.x * 4 + (threadIdx.x >> 6);
    if (k >= nb_he + nb_nd) return;
    int lane = threadIdx.x & 63;
    const int* counts = (k < nb_he) ? counts_he : counts_nd;
    int nb = (k < nb_he) ? nb_he : nb_nd;
    int kk = (k < nb_he) ? k : k - nb_he;
    int s = 0;
    for (int b = lane; b < nblk; b += 64) s += counts[(size_t)b * nb + kk];
    #pragma unroll
    for (int off = 1; off < 64; off <<= 1) s += __shfl_xor(s, off);
    if (lane == 0) btot[k] = s;
}

__global__ void bucket_scan2(const int* __restrict__ btot, int* __restrict__ bbase,
                             int* __restrict__ he_ptr, int* __restrict__ nd_ptr,
                             int nseg_he, int nseg_nd, int nb_he, int nb_nd, int Etot)
{
    __shared__ int wsum[16];
    const int side = blockIdx.x;
    const int nb   = side ? nb_nd : nb_he;
    const int off0 = side ? nb_he : 0;
    int* ptr       = side ? nd_ptr : he_ptr;
    const int nseg = side ? nseg_nd : nseg_he;
    const int tid = threadIdx.x, lane = tid & 63, wid = tid >> 6;
    int v = (tid < nb) ? btot[off0 + tid] : 0;
    int x = v;
    #pragma unroll
    for (int off = 1; off < 64; off <<= 1) {
        int y = __shfl_up(x, off);
        if (lane >= off) x += y;
    }
    if (lane == 63) wsum[wid] = x;
    __syncthreads();
    if (wid == 0) {
        int wv = (lane < 16) ? wsum[lane] : 0;
        #pragma unroll
        for (int off = 1; off < 16; off <<= 1) {
            int y = __shfl_up(wv, off);
            if (lane >= off) wv += y;
        }
        if (lane < 16) wsum[lane] = wv;
    }
    __syncthreads();
    int base = (wid > 0) ? wsum[wid - 1] : 0;
    if (tid < nb) bbase[off0 + tid] = base + x - v;
    if (tid == 0) ptr[nseg] = Etot;
}

template<int SHIFT>
__global__ __launch_bounds__(256) void fill_csr(
    const unsigned* __restrict__ staging, const int* __restrict__ counts,
    const int* __restrict__ boffs, const int* __restrict__ bbase,
    int* __restrict__ ptr, int* __restrict__ outv,
    int nseg, int nb, int nblk)
{
    __shared__ int cur[1 << SHIFT];
    const int tid = threadIdx.x;
    const int k   = blockIdx.x;
    const int s0  = k << SHIFT;
    const int NS  = min(1 << SHIFT, nseg - s0);
    for (int i = tid; i < NS; i += 256) cur[i] = 0;
    __syncthreads();
    for (int b = tid; b < nblk; b += 256) {
        int c   = counts[(size_t)b * nb + k];
        int off = b * BIN_CH + boffs[(size_t)b * nb + k];
        for (int i = 0; i < c; ++i) {
            int sl = (int)(staging[off + i] >> 20);
            atomicAdd(&cur[sl], 1);
        }
    }
    __syncthreads();
    if (tid == 0) {
        int run = bbase[k];
        for (int i = 0; i < NS; ++i) {
            int c = cur[i];
            cur[i] = run;
            ptr[s0 + i] = run;
            run += c;
        }
    }
    __syncthreads();
    for (int b = tid; b < nblk; b += 256) {
        int c   = counts[(size_t)b * nb + k];
        int off = b * BIN_CH + boffs[(size_t)b * nb + k];
        for (int i = 0; i < c; ++i) {
            unsigned pv = staging[off + i];
            int pos = atomicAdd(&cur[pv >> 20], 1);
            outv[pos] = (int)(pv & 0xFFFFFu);
        }
    }
}

// ---------------------------------------------------------------------------
// FUSED: nd-side fill_csr<7> blocks ++ he-gather blocks (independent work).
// Blocks [0, nb_nd): fill nd CSR from staging_nd (streaming).
// Blocks [nb_nd, ...): gather_he (latency-bound K-row gather); the fill
// streams under the gather's memory latency.
// ---------------------------------------------------------------------------
__global__ __launch_bounds__(256) void fill7_gather(
    const unsigned* __restrict__ staging_nd, const int* __restrict__ counts_nd,
    const int* __restrict__ boffs_nd, const int* __restrict__ bbase_nd,
    int* __restrict__ nd_ptr, int* __restrict__ nd_he,
    int nseg_nd, int nb_nd, int nblk,
    const uint2* __restrict__ K2, const int* __restrict__ he_ptr,
    const int* __restrict__ members, uint2* __restrict__ he_feat2, int HE)
{
    const int tid = threadIdx.x;
    if ((int)blockIdx.x < nb_nd) {
        // ---- fill_csr<7> path ----
        __shared__ int cur[128];
        const int k  = blockIdx.x;
        const int s0 = k << 7;
        const int NS = min(128, nseg_nd - s0);
        for (int i = tid; i < NS; i += 256) cur[i] = 0;
        __syncthreads();
        for (int b = tid; b < nblk; b += 256) {
            int c   = counts_nd[(size_t)b * nb_nd + k];
            int off = b * BIN_CH + boffs_nd[(size_t)b * nb_nd + k];
            for (int i = 0; i < c; ++i) {
                int sl = (int)(staging_nd[off + i] >> 20);
                atomicAdd(&cur[sl], 1);
            }
        }
        __syncthreads();
        if (tid == 0) {
            int run = bbase_nd[k];
            for (int i = 0; i < NS; ++i) {
                int c = cur[i];
                cur[i] = run;
                nd_ptr[s0 + i] = run;
                run += c;
            }
        }
        __syncthreads();
        for (int b = tid; b < nblk; b += 256) {
            int c   = counts_nd[(size_t)b * nb_nd + k];
            int off = b * BIN_CH + boffs_nd[(size_t)b * nb_nd + k];
            for (int i = 0; i < c; ++i) {
                unsigned pv = staging_nd[off + i];
                int pos = atomicAdd(&cur[pv >> 20], 1);
                nd_he[pos] = (int)(pv & 0xFFFFFu);
            }
        }
    } else {
        // ---- gather_he path (identical math to R19) ----
        int h = (blockIdx.x - nb_nd) * 4 + (tid >> 6);
        if (h >= HE) return;
        unsigned lane = tid & 63;
        unsigned half = lane >> 5;
        unsigned q    = lane & 31;
        int beg = he_ptr[h], end = he_ptr[h + 1];
        float a0 = 0.f, a1 = 0.f, a2 = 0.f, a3 = 0.f;
        int p = beg;
        for (; p + 7 < end; p += 8) {
            unsigned nA = (unsigned)members[p     + half];
            unsigned nB = (unsigned)members[p + 2 + half];
            unsigned nC = (unsigned)members[p + 4 + half];
            unsigned nD = (unsigned)members[p + 6 + half];
            uint2 uA = K2[(nA << 5) + q];
            uint2 uB = K2[(nB << 5) + q];
            uint2 uC = K2[(nC << 5) + q];
            uint2 uD = K2[(nD << 5) + q];
            a0 += (bflo(uA.x) + bflo(uB.x)) + (bflo(uC.x) + bflo(uD.x));
            a1 += (bfhi(uA.x) + bfhi(uB.x)) + (bfhi(uC.x) + bfhi(uD.x));
            a2 += (bflo(uA.y) + bflo(uB.y)) + (bflo(uC.y) + bflo(uD.y));
            a3 += (bfhi(uA.y) + bfhi(uB.y)) + (bfhi(uC.y) + bfhi(uD.y));
        }
        for (; p < end; p += 2) {
            int pi = p + (int)half;
            bool valid = pi < end;
            unsigned nn = (unsigned)members[valid ? pi : beg];
            uint2 u = K2[(nn << 5) + q];
            float w = valid ? 1.f : 0.f;
            a0 += w * bflo(u.x);
            a1 += w * bfhi(u.x);
            a2 += w * bflo(u.y);
            a3 += w * bfhi(u.y);
        }
        a0 += __shfl_xor(a0, 32);
        a1 += __shfl_xor(a1, 32);
        a2 += __shfl_xor(a2, 32);
        a3 += __shfl_xor(a3, 32);
        if (half == 0)
            he_feat2[((unsigned)h << 5) + q] = make_uint2(packbf(a0, a1), packbf(a2, a3));
    }
}

// ---------------------------------------------------------------------------
// Stages 3-5 fused: per-node online softmax + weighted accumulate.
// ---------------------------------------------------------------------------
__global__ void fused_attn(const uint2* __restrict__ Qb,
                           const uint2* __restrict__ he_feat2,
                           const int* __restrict__ node_ptr,
                           const int* __restrict__ hes,
                           uint2* __restrict__ node_out_bf, int N)
{
    const float SCL = 0.17677669529663687f * 1.4426950408889634f;
    const float NEG = -1e30f;
    int n = blockIdx.x * 4 + (threadIdx.x >> 6);
    if (n >= N) return;
    unsigned lane = threadIdx.x & 63;
    unsigned half = lane >> 5;
    unsigned q    = lane & 31;
    int beg = node_ptr[n], end = node_ptr[n + 1];
    uint2 qu = Qb[((unsigned)n << 5) + q];
    float4 q4;
    q4.x = bflo(qu.x) * SCL; q4.y = bfhi(qu.x) * SCL;
    q4.z = bflo(qu.y) * SCL; q4.w = bfhi(qu.y) * SCL;
    float m = NEG, s = 0.f;
    float a0 = 0.f, a1 = 0.f, a2 = 0.f, a3 = 0.f;

    for (int p = beg; p < end; p += 8) {
        const int last = end - 1;
        int iA = p     + (int)half, iB = p + 2 + (int)half;
        int iC = p + 4 + (int)half, iD = p + 6 + (int)half;
        bool vA = iA <= last, vB = iB <= last, vC = iC <= last, vD = iD <= last;
        unsigned hA = (unsigned)hes[vA ? iA : last];
        unsigned hB = (unsigned)hes[vB ? iB : last];
        unsigned hC = (unsigned)hes[vC ? iC : last];
        unsigned hD = (unsigned)hes[vD ? iD : last];
        uint2 uA = he_feat2[(hA << 5) + q];
        uint2 uB = he_feat2[(hB << 5) + q];
        uint2 uC = he_feat2[(hC << 5) + q];
        uint2 uD = he_feat2[(hD << 5) + q];
        float fA0 = bflo(uA.x), fA1 = bfhi(uA.x), fA2 = bflo(uA.y), fA3 = bfhi(uA.y);
        float fB0 = bflo(uB.x), fB1 = bfhi(uB.x), fB2 = bflo(uB.y), fB3 = bfhi(uB.y);
        float fC0 = bflo(uC.x), fC1 = bfhi(uC.x), fC2 = bflo(uC.y), fC3 = bfhi(uC.y);
        float fD0 = bflo(uD.x), fD1 = bfhi(uD.x), fD2 = bflo(uD.y), fD3 = bfhi(uD.y);
        float dA = q4.x * fA0 + q4.y * fA1 + q4.z * fA2 + q4.w * fA3;
        float dB = q4.x * fB0 + q4.y * fB1 + q4.z * fB2 + q4.w * fB3;
        float dC = q4.x * fC0 + q4.y * fC1 + q4.z * fC2 + q4.w * fC3;
        float dD = q4.x * fD0 + q4.y * fD1 + q4.z * fD2 + q4.w * fD3;
        dA = red8(dA); dB = red8(dB); dC = red8(dC); dD = red8(dD);
        float aA = vA ? dA : NEG;
        float aB = vB ? dB : NEG;
        float aC = vC ? dC : NEG;
        float aD = vD ? dD : NEG;
        float newm = fmaxf(m, fmaxf(fmaxf(aA, aB), fmaxf(aC, aD)));
        float scale = fexp2(m - newm);
        float wA = fexp2(aA - newm), wB = fexp2(aB - newm);
        float wC = fexp2(aC - newm), wD = fexp2(aD - newm);
        s  = s  * scale + ((wA + wB) + (wC + wD));
        a0 = a0 * scale + ((wA * fA0 + wB * fB0) + (wC * fC0 + wD * fD0));
        a1 = a1 * scale + ((wA * fA1 + wB * fB1) + (wC * fC1 + wD * fD1));
        a2 = a2 * scale + ((wA * fA2 + wB * fB2) + (wC * fC2 + wD * fD2));
        a3 = a3 * scale + ((wA * fA3 + wB * fB3) + (wC * fC3 + wD * fD3));
        m = newm;
    }

    float mo = __shfl_xor(m, 32);
    float so = __shfl_xor(s, 32);
    float b0 = __shfl_xor(a0, 32);
    float b1 = __shfl_xor(a1, 32);
    float b2 = __shfl_xor(a2, 32);
    float b3 = __shfl_xor(a3, 32);
    float M  = fmaxf(m, mo);
    float e1 = fexp2(m - M), e2 = fexp2(mo - M);
    float S  = s * e1 + so * e2;
    float inv = 1.f / (S + 1e-16f);
    if (half == 0) {
        float o0 = (a0 * e1 + b0 * e2) * inv;
        float o1 = (a1 * e1 + b1 * e2) * inv;
        float o2 = (a2 * e1 + b2 * e2) * inv;
        float o3 = (a3 * e1 + b3 * e2) * inv;
        node_out_bf[((unsigned)n << 5) + q] = make_uint2(packbf(o0, o1), packbf(o2, o3));
    }
}

// ---------------------------------------------------------------------------
extern "C" void kernel_launch(void* const* d_in, const int* in_sizes, int n_in,
                              void* d_out, int out_size, void* d_ws, size_t ws_size,
                              hipStream_t stream)
{
    const float* x        = (const float*)d_in[0];
    const int*   node_idx = (const int*)d_in[1];
    const int*   he_idx   = (const int*)d_in[2];
    const float* Wk       = (const float*)d_in[3];
    const float* bk       = (const float*)d_in[4];
    const float* Wq       = (const float*)d_in[5];
    const float* bq       = (const float*)d_in[6];
    const float* Wa       = (const float*)d_in[7];
    const float* ba       = (const float*)d_in[8];
    float*       out      = (float*)d_out;

    const int N = in_sizes[0] / D;
    const int E = in_sizes[1];

    const int nblk  = (E + BIN_CH - 1) / BIN_CH;
    const int nb_he = (NUM_HE + 31) >> 5;    // 625 buckets of 32 hyperedges
    const int nb_nd = (N + 127) >> 7;        // 782 buckets of 128 nodes
    const int ggrid = (N + 127) / 128;

    // Workspace layout.
    float* ws      = (float*)d_ws;
    float* Kbuf    = ws;                               // N*D region: bf16 K, later bf16 node_out
    float* Qbuf    = Kbuf    + (size_t)N * D;          // N*D region (bf16 Q in half)
    float* he_feat = Qbuf    + (size_t)N * D;          // NUM_HE*D region (bf16 in half)
    unsigned short* wfrag = (unsigned short*)(he_feat + (size_t)NUM_HE * D); // 3*32768
    int*   ibase     = (int*)(wfrag + 3 * 32768);
    int*   he_ptr    = ibase;                            // NUM_HE+1
    int*   nd_ptr    = he_ptr    + (NUM_HE + 1);         // N+1
    int*   he_mem    = nd_ptr    + (N + 1);              // E (node ids by he)
    int*   nd_he     = he_mem    + E;                    // E (he ids by node)
    int*   counts_he = nd_he     + E;                    // nblk*nb_he
    int*   boffs_he  = counts_he + (size_t)nblk * nb_he; // nblk*nb_he
    int*   counts_nd = boffs_he  + (size_t)nblk * nb_he; // nblk*nb_nd
    int*   boffs_nd  = counts_nd + (size_t)nblk * nb_nd; // nblk*nb_nd
    int*   btot      = boffs_nd  + (size_t)nblk * nb_nd; // nb_he+nb_nd
    int*   bbase     = btot      + (nb_he + nb_nd);      // nb_he+nb_nd
    unsigned* staging_he = (unsigned*)(bbase + (nb_he + nb_nd)); // E
    unsigned* staging_nd = staging_he + E;                        // E

    // W fragments (hi/lo) for all three projections
    wprep<<<(3 * 16384 + 255) / 256, 256, 0, stream>>>(Wk, Wq, Wa, wfrag);

    // Stage 1 + binning fused: gemm blocks ++ binning blocks (independent)
    gemm_kq_stage<<<ggrid + nblk, 256, 0, stream>>>(
        x, wfrag, wfrag + 32768, wfrag + 49152,
        bk, bq, (unsigned short*)Kbuf, (unsigned short*)Qbuf, N, ggrid,
        he_idx, node_idx,
        counts_he, boffs_he, staging_he,
        counts_nd, boffs_nd, staging_nd, E, nb_he, nb_nd);

    bucket_tot2<<<(nb_he + nb_nd + 3) / 4, 256, 0, stream>>>(
        counts_he, counts_nd, btot, nb_he, nb_nd, nblk);
    bucket_scan2<<<2, 1024, 0, stream>>>(
        btot, bbase, he_ptr, nd_ptr, NUM_HE, N, nb_he, nb_nd, E);

    // he-side CSR fill
    fill_csr<5><<<nb_he, 256, 0, stream>>>(
        staging_he, counts_he, boffs_he, bbase, he_ptr, he_mem, NUM_HE, nb_he, nblk);

    // Fused: nd-side CSR fill ++ he-gather (independent)
    fill7_gather<<<nb_nd + (NUM_HE + 3) / 4, 256, 0, stream>>>(
        staging_nd, counts_nd, boffs_nd, bbase + nb_he, nd_ptr, nd_he,
        N, nb_nd, nblk,
        (const uint2*)Kbuf, he_ptr, he_mem, (uint2*)he_feat, NUM_HE);

    // Stages 3-5: fused attention (bf16 K dead; Kbuf region becomes bf16 node_out)
    fused_attn<<<(N + 3) / 4, 256, 0, stream>>>(
        (const uint2*)Qbuf, (const uint2*)he_feat, nd_ptr, nd_he, (uint2*)Kbuf, N);

    // Stage 6: residual (x fp32) + bf16 node_out @ Wa
    gemm_out<<<(N + 127) / 128, 256, 0, stream>>>(
        (const unsigned short*)Kbuf, x, wfrag + 65536, wfrag + 81920, ba, out, N);
}

// Round 23
// 227.908 us; speedup vs baseline: 1.1113x; 1.0432x over previous
//
#include <hip/hip_runtime.h>
#include <math.h>

#define D 128
#define HEADS 4
#define DK 32
#define NUM_HE 20000
#define BIN_CH 4096

typedef short bf16x8 __attribute__((ext_vector_type(8)));
typedef float f32x4  __attribute__((ext_vector_type(4)));

__device__ __forceinline__ unsigned short f2bf(float f) {
    unsigned int u = __float_as_uint(f);
    u = (u + 0x7fffu + ((u >> 16) & 1u)) >> 16;
    return (unsigned short)u;
}
__device__ __forceinline__ float bf2f(unsigned short h) {
    return __uint_as_float(((unsigned int)h) << 16);
}
__device__ __forceinline__ float bflo(unsigned int u) {
    return __uint_as_float(u << 16);
}
__device__ __forceinline__ float bfhi(unsigned int u) {
    return __uint_as_float(u & 0xffff0000u);
}
__device__ __forceinline__ unsigned int packbf(float lo, float hi) {
    return (unsigned int)f2bf(lo) | ((unsigned int)f2bf(hi) << 16);
}
// raw v_exp_f32: computes 2^x in one VALU instruction (ISA §3)
__device__ __forceinline__ float fexp2(float x) {
    float r;
    asm("v_exp_f32 %0, %1" : "=v"(r) : "v"(x));
    return r;
}
// butterfly add over 8-lane groups via DPP (VALU pipe, no LDS)
template<int CTRL>
__device__ __forceinline__ float dppadd(float v) {
    int s = __builtin_amdgcn_update_dpp(0, __float_as_int(v), CTRL, 0xf, 0xf, true);
    return v + __int_as_float(s);
}
__device__ __forceinline__ float red8(float v) {
    v = dppadd<0xB1>(v);    // quad_perm [1,0,3,2]  (xor 1)
    v = dppadd<0x4E>(v);    // quad_perm [2,3,0,1]  (xor 2)
    v = dppadd<0x141>(v);   // row_half_mirror      (xor 4 equivalent)
    return v;
}

// ---------------------------------------------------------------------------
// W preprocessing: fragment-order Wk|Wq|Wa as bf16 hi/lo.
// ---------------------------------------------------------------------------
__global__ void wprep(const float* __restrict__ Wk, const float* __restrict__ Wq,
                      const float* __restrict__ Wa, unsigned short* __restrict__ dst)
{
    int t = blockIdx.x * blockDim.x + threadIdx.x;
    if (t >= 3 * 16384) return;
    int w = t >> 14, rem = t & 16383;
    int ks = rem >> 12, nf = (rem >> 9) & 7, lane = (rem >> 3) & 63, j = rem & 7;
    int r = ks * 32 + (lane >> 4) * 8 + j;
    int c = nf * 16 + (lane & 15);
    const float* W = (w == 0) ? Wk : (w == 1) ? Wq : Wa;
    float v = W[r * 128 + c];
    unsigned short h = f2bf(v);
    dst[(size_t)w * 32768 + rem]         = h;
    dst[(size_t)w * 32768 + 16384 + rem] = f2bf(v - bf2f(h));
}

// ---------------------------------------------------------------------------
// LDS exclusive scan helper for the binning path.
// ---------------------------------------------------------------------------
__device__ __forceinline__ void lds_exscan(int* hist, int* offs, int* wtot,
                                           int nb, int tid, int lane, int wid)
{
    const int i0 = tid * 4;
    int v0 = (i0 + 0 < nb) ? hist[i0 + 0] : 0;
    int v1 = (i0 + 1 < nb) ? hist[i0 + 1] : 0;
    int v2 = (i0 + 2 < nb) ? hist[i0 + 2] : 0;
    int v3 = (i0 + 3 < nb) ? hist[i0 + 3] : 0;
    int tsum = v0 + v1 + v2 + v3;
    int x = tsum;
    #pragma unroll
    for (int off = 1; off < 64; off <<= 1) {
        int y = __shfl_up(x, off);
        if (lane >= off) x += y;
    }
    if (lane == 63) wtot[wid] = x;
    __syncthreads();
    if (tid == 0) {
        int r = 0;
        #pragma unroll
        for (int w = 0; w < 4; ++w) { int c = wtot[w]; wtot[w] = r; r += c; }
    }
    __syncthreads();
    int base = wtot[wid] + x - tsum;
    if (i0 + 0 < nb) offs[i0 + 0] = base; base += v0;
    if (i0 + 1 < nb) offs[i0 + 1] = base; base += v1;
    if (i0 + 2 < nb) offs[i0 + 2] = base; base += v2;
    if (i0 + 3 < nb) offs[i0 + 3] = base;
    __syncthreads();
}

// ---------------------------------------------------------------------------
// FUSED: K+Q projection blocks ++ two-sided binning blocks (R20 winner).
// ---------------------------------------------------------------------------
__global__ __launch_bounds__(256) void gemm_kq_stage(
    const float* __restrict__ A,
    const unsigned short* __restrict__ BhK,
    const unsigned short* __restrict__ BhQ, const unsigned short* __restrict__ BlQ,
    const float* __restrict__ bk, const float* __restrict__ bq,
    unsigned short* __restrict__ K, unsigned short* __restrict__ Q, int M, int ggrid,
    const int* __restrict__ he_idx, const int* __restrict__ nd_idx,
    int* __restrict__ counts_he, int* __restrict__ boffs_he,
    unsigned* __restrict__ staging_he,
    int* __restrict__ counts_nd, int* __restrict__ boffs_nd,
    unsigned* __restrict__ staging_nd,
    int E, int nb_he, int nb_nd)
{
    __shared__ int smem[8192];   // 32 KB shared by both paths
    const int tid = threadIdx.x;

    if (blockIdx.x < ggrid) {
        // ================= GEMM path ==========
        unsigned short (*tile)[32][128] = (unsigned short (*)[32][128])smem;
        const int lane = tid & 63;
        const int wv   = tid >> 6;
        const int r0   = blockIdx.x * 128 + wv * 32;
        const int lr   = lane & 15;
        const int kg   = lane >> 4;
        unsigned short (*mytile)[128] = tile[wv];

        f32x4 ack[2][8], acq[2][8];
        #pragma unroll
        for (int m = 0; m < 2; ++m)
            #pragma unroll
            for (int n = 0; n < 8; ++n) {
                ack[m][n] = (f32x4){0.f, 0.f, 0.f, 0.f};
                acq[m][n] = (f32x4){0.f, 0.f, 0.f, 0.f};
            }

        int row[2];
        row[0] = min(r0 + lr,      M - 1);
        row[1] = min(r0 + 16 + lr, M - 1);

        for (int ks = 0; ks < 4; ++ks) {
            bf16x8 ah[2], al[2];
            #pragma unroll
            for (int m = 0; m < 2; ++m) {
                const float* p = A + (size_t)row[m] * D + ks * 32 + kg * 8;
                float4 v0 = *(const float4*)p;
                float4 v1 = *(const float4*)(p + 4);
                float vv[8] = {v0.x, v0.y, v0.z, v0.w, v1.x, v1.y, v1.z, v1.w};
                #pragma unroll
                for (int j = 0; j < 8; ++j) {
                    unsigned short h = f2bf(vv[j]);
                    ah[m][j] = (short)h;
                    al[m][j] = (short)f2bf(vv[j] - bf2f(h));
                }
            }
            #pragma unroll
            for (int nf = 0; nf < 8; ++nf) {
                const int boff = ((ks * 8 + nf) * 64 + lane) * 8;
                bf16x8 bhk = *(const bf16x8*)(const void*)(BhK + boff);
                bf16x8 bhq = *(const bf16x8*)(const void*)(BhQ + boff);
                bf16x8 blq = *(const bf16x8*)(const void*)(BlQ + boff);
                #pragma unroll
                for (int m = 0; m < 2; ++m) {
                    ack[m][nf] = __builtin_amdgcn_mfma_f32_16x16x32_bf16(ah[m], bhk, ack[m][nf], 0, 0, 0);
                    acq[m][nf] = __builtin_amdgcn_mfma_f32_16x16x32_bf16(ah[m], bhq, acq[m][nf], 0, 0, 0);
                    acq[m][nf] = __builtin_amdgcn_mfma_f32_16x16x32_bf16(ah[m], blq, acq[m][nf], 0, 0, 0);
                    acq[m][nf] = __builtin_amdgcn_mfma_f32_16x16x32_bf16(al[m], bhq, acq[m][nf], 0, 0, 0);
                }
            }
        }

        // K epilogue: stage (swizzled) -> coalesced 256B rows
        #pragma unroll
        for (int nf = 0; nf < 8; ++nf) {
            int col = nf * 16 + lr;
            float bkv = bk[col];
            int colp = col ^ (kg << 4);
            #pragma unroll
            for (int m = 0; m < 2; ++m)
                #pragma unroll
                for (int j = 0; j < 4; ++j)
                    mytile[m * 16 + kg * 4 + j][colp] = f2bf(ack[m][nf][j] + bkv);
        }
        #pragma unroll
        for (int it = 0; it < 8; ++it) {
            int idx  = it * 64 + lane;
            int lrow = idx >> 4;
            int chnk = idx & 15;
            int pch  = chnk ^ (((lrow >> 2) & 3) << 1);
            uint4 v = *(const uint4*)&mytile[lrow][pch * 8];
            int gr = r0 + lrow;
            if (gr < M) *(uint4*)(K + (size_t)gr * D + chnk * 8) = v;
        }

        // Q epilogue (reuse the tile)
        #pragma unroll
        for (int nf = 0; nf < 8; ++nf) {
            int col = nf * 16 + lr;
            float bqv = bq[col];
            int colp = col ^ (kg << 4);
            #pragma unroll
            for (int m = 0; m < 2; ++m)
                #pragma unroll
                for (int j = 0; j < 4; ++j)
                    mytile[m * 16 + kg * 4 + j][colp] = f2bf(acq[m][nf][j] + bqv);
        }
        #pragma unroll
        for (int it = 0; it < 8; ++it) {
            int idx  = it * 64 + lane;
            int lrow = idx >> 4;
            int chnk = idx & 15;
            int pch  = chnk ^ (((lrow >> 2) & 3) << 1);
            uint4 v = *(const uint4*)&mytile[lrow][pch * 8];
            int gr = r0 + lrow;
            if (gr < M) *(uint4*)(Q + (size_t)gr * D + chnk * 8) = v;
        }
    } else {
        // ================= Binning path ====
        const int bid  = blockIdx.x - ggrid;
        const int lane = tid & 63, wid = tid >> 6;
        const int e0   = bid * BIN_CH;
        int* hist_he = smem;             // 640
        int* offs_he = hist_he + 640;    // 640
        int* hist_nd = offs_he + 640;    // 800
        int* offs_nd = hist_nd + 800;    // 800
        int* wtot    = offs_nd + 800;    // 4

        for (int i = tid; i < nb_he; i += 256) hist_he[i] = 0;
        for (int i = tid; i < nb_nd; i += 256) hist_nd[i] = 0;
        __syncthreads();

        int myhe[16], mynd[16], rhe[16], rnd[16];
        #pragma unroll
        for (int j = 0; j < 16; ++j) {
            int e = e0 + j * 256 + tid;
            if (e < E) {
                int h = he_idx[e], n = nd_idx[e];
                myhe[j] = h; mynd[j] = n;
                rhe[j] = atomicAdd(&hist_he[h >> 5], 1);
                rnd[j] = atomicAdd(&hist_nd[n >> 7], 1);
            } else myhe[j] = -1;
        }
        __syncthreads();

        lds_exscan(hist_he, offs_he, wtot, nb_he, tid, lane, wid);
        lds_exscan(hist_nd, offs_nd, wtot, nb_nd, tid, lane, wid);

        for (int i = tid; i < nb_he; i += 256) {
            counts_he[(size_t)bid * nb_he + i] = hist_he[i];
            boffs_he [(size_t)bid * nb_he + i] = offs_he[i];
        }
        for (int i = tid; i < nb_nd; i += 256) {
            counts_nd[(size_t)bid * nb_nd + i] = hist_nd[i];
            boffs_nd [(size_t)bid * nb_nd + i] = offs_nd[i];
        }
        #pragma unroll
        for (int j = 0; j < 16; ++j) {
            if (myhe[j] >= 0) {
                int bh = myhe[j] >> 5;
                staging_he[e0 + offs_he[bh] + rhe[j]] =
                    ((unsigned)(myhe[j] & 31) << 20) | (unsigned)mynd[j];
                int bn = mynd[j] >> 7;
                staging_nd[e0 + offs_nd[bn] + rnd[j]] =
                    ((unsigned)(mynd[j] & 127) << 20) | (unsigned)myhe[j];
            }
        }
    }
}

// ---------------------------------------------------------------------------
// Output projection: A = bf16 node_out + fp32 residual x; fp32 out.
// ---------------------------------------------------------------------------
__global__ __launch_bounds__(256) void gemm_out(
    const unsigned short* __restrict__ A, const float* __restrict__ R,
    const unsigned short* __restrict__ Bh, const unsigned short* __restrict__ Bl,
    const float* __restrict__ bias, float* __restrict__ C, int M)
{
    const int lane = threadIdx.x & 63;
    const int wv   = threadIdx.x >> 6;
    const int r0   = blockIdx.x * 128 + wv * 32;
    const int lr   = lane & 15;
    const int kg   = lane >> 4;

    f32x4 acc[2][8];
    #pragma unroll
    for (int m = 0; m < 2; ++m)
        #pragma unroll
        for (int n = 0; n < 8; ++n) acc[m][n] = (f32x4){0.f, 0.f, 0.f, 0.f};

    int row[2];
    row[0] = min(r0 + lr,      M - 1);
    row[1] = min(r0 + 16 + lr, M - 1);

    for (int ks = 0; ks < 4; ++ks) {
        bf16x8 ah[2], al[2];
        #pragma unroll
        for (int m = 0; m < 2; ++m) {
            const unsigned short* pa = A + (size_t)row[m] * D + ks * 32 + kg * 8;
            uint4 av = *(const uint4*)(const void*)pa;
            const float* q = R + (size_t)row[m] * D + ks * 32 + kg * 8;
            float4 u0 = *(const float4*)q;
            float4 u1 = *(const float4*)(q + 4);
            float vv[8];
            vv[0] = bflo(av.x) + u0.x; vv[1] = bfhi(av.x) + u0.y;
            vv[2] = bflo(av.y) + u0.z; vv[3] = bfhi(av.y) + u0.w;
            vv[4] = bflo(av.z) + u1.x; vv[5] = bfhi(av.z) + u1.y;
            vv[6] = bflo(av.w) + u1.z; vv[7] = bfhi(av.w) + u1.w;
            #pragma unroll
            for (int j = 0; j < 8; ++j) {
                unsigned short h = f2bf(vv[j]);
                ah[m][j] = (short)h;
                al[m][j] = (short)f2bf(vv[j] - bf2f(h));
            }
        }
        #pragma unroll
        for (int nf = 0; nf < 8; ++nf) {
            const int boff = ((ks * 8 + nf) * 64 + lane) * 8;
            bf16x8 bh = *(const bf16x8*)(const void*)(Bh + boff);
            bf16x8 bl = *(const bf16x8*)(const void*)(Bl + boff);
            #pragma unroll
            for (int m = 0; m < 2; ++m) {
                acc[m][nf] = __builtin_amdgcn_mfma_f32_16x16x32_bf16(ah[m], bh, acc[m][nf], 0, 0, 0);
                acc[m][nf] = __builtin_amdgcn_mfma_f32_16x16x32_bf16(ah[m], bl, acc[m][nf], 0, 0, 0);
                acc[m][nf] = __builtin_amdgcn_mfma_f32_16x16x32_bf16(al[m], bh, acc[m][nf], 0, 0, 0);
            }
        }
    }

    #pragma unroll
    for (int nf = 0; nf < 8; ++nf) {
        int col = nf * 16 + lr;
        float bv = bias[col];
        #pragma unroll
        for (int m = 0; m < 2; ++m) {
            #pragma unroll
            for (int j = 0; j < 4; ++j) {
                int gr = r0 + m * 16 + kg * 4 + j;
                if (gr < M) C[(size_t)gr * D + col] = acc[m][nf][j] + bv;
            }
        }
    }
}

__global__ void bucket_tot2(const int* __restrict__ counts_he,
                            const int* __restrict__ counts_nd,
                            int* __restrict__ btot, int nb_he, int nb_nd, int nblk)
{
    int k = blockIdx.x * 4 + (threadIdx.x >> 6);
    if (k >= nb_he + nb_nd) return;
    int lane = threadIdx.x & 63;
    const int* counts = (k < nb_he) ? counts_he : counts_nd;
    int nb = (k < nb_he) ? nb_he : nb_nd;
    int kk = (k < nb_he) ? k : k - nb_he;
    int s = 0;
    for (int b = lane; b < nblk; b += 64) s += counts[(size_t)b * nb + kk];
    #pragma unroll
    for (int off = 1; off < 64; off <<= 1) s += __shfl_xor(s, off);
    if (lane == 0) btot[k] = s;
}

__global__ void bucket_scan2(const int* __restrict__ btot, int* __restrict__ bbase,
                             int* __restrict__ he_ptr, int* __restrict__ nd_ptr,
                             int nseg_he, int nseg_nd, int nb_he, int nb_nd, int Etot)
{
    __shared__ int wsum[16];
    const int side = blockIdx.x;
    const int nb   = side ? nb_nd : nb_he;
    const int off0 = side ? nb_he : 0;
    int* ptr       = side ? nd_ptr : he_ptr;
    const int nseg = side ? nseg_nd : nseg_he;
    const int tid = threadIdx.x, lane = tid & 63, wid = tid >> 6;
    int v = (tid < nb) ? btot[off0 + tid] : 0;
    int x = v;
    #pragma unroll
    for (int off = 1; off < 64; off <<= 1) {
        int y = __shfl_up(x, off);
        if (lane >= off) x += y;
    }
    if (lane == 63) wsum[wid] = x;
    __syncthreads();
    if (wid == 0) {
        int wv = (lane < 16) ? wsum[lane] : 0;
        #pragma unroll
        for (int off = 1; off < 16; off <<= 1) {
            int y = __shfl_up(wv, off);
            if (lane >= off) wv += y;
        }
        if (lane < 16) wsum[lane] = wv;
    }
    __syncthreads();
    int base = (wid > 0) ? wsum[wid - 1] : 0;
    if (tid < nb) bbase[off0 + tid] = base + x - v;
    if (tid == 0) ptr[nseg] = Etot;
}

template<int SHIFT>
__global__ __launch_bounds__(256) void fill_csr(
    const unsigned* __restrict__ staging, const int* __restrict__ counts,
    const int* __restrict__ boffs, const int* __restrict__ bbase,
    int* __restrict__ ptr, int* __restrict__ outv,
    int nseg, int nb, int nblk)
{
    __shared__ int cur[1 << SHIFT];
    const int tid = threadIdx.x;
    const int k   = blockIdx.x;
    const int s0  = k << SHIFT;
    const int NS  = min(1 << SHIFT, nseg - s0);
    for (int i = tid; i < NS; i += 256) cur[i] = 0;
    __syncthreads();
    for (int b = tid; b < nblk; b += 256) {
        int c   = counts[(size_t)b * nb + k];
        int off = b * BIN_CH + boffs[(size_t)b * nb + k];
        for (int i = 0; i < c; ++i) {
            int sl = (int)(staging[off + i] >> 20);
            atomicAdd(&cur[sl], 1);
        }
    }
    __syncthreads();
    if (tid == 0) {
        int run = bbase[k];
        for (int i = 0; i < NS; ++i) {
            int c = cur[i];
            cur[i] = run;
            ptr[s0 + i] = run;
            run += c;
        }
    }
    __syncthreads();
    for (int b = tid; b < nblk; b += 256) {
        int c   = counts[(size_t)b * nb + k];
        int off = b * BIN_CH + boffs[(size_t)b * nb + k];
        for (int i = 0; i < c; ++i) {
            unsigned pv = staging[off + i];
            int pos = atomicAdd(&cur[pv >> 20], 1);
            outv[pos] = (int)(pv & 0xFFFFFu);
        }
    }
}

// ---------------------------------------------------------------------------
// FUSED: nd-side fill_csr<7> blocks ++ he-gather blocks (independent work).
// ---------------------------------------------------------------------------
__global__ __launch_bounds__(256) void fill7_gather(
    const unsigned* __restrict__ staging_nd, const int* __restrict__ counts_nd,
    const int* __restrict__ boffs_nd, const int* __restrict__ bbase_nd,
    int* __restrict__ nd_ptr, int* __restrict__ nd_he,
    int nseg_nd, int nb_nd, int nblk,
    const uint2* __restrict__ K2, const int* __restrict__ he_ptr,
    const int* __restrict__ members, uint2* __restrict__ he_feat2, int HE)
{
    const int tid = threadIdx.x;
    if ((int)blockIdx.x < nb_nd) {
        // ---- fill_csr<7> path ----
        __shared__ int cur[128];
        const int k  = blockIdx.x;
        const int s0 = k << 7;
        const int NS = min(128, nseg_nd - s0);
        for (int i = tid; i < NS; i += 256) cur[i] = 0;
        __syncthreads();
        for (int b = tid; b < nblk; b += 256) {
            int c   = counts_nd[(size_t)b * nb_nd + k];
            int off = b * BIN_CH + boffs_nd[(size_t)b * nb_nd + k];
            for (int i = 0; i < c; ++i) {
                int sl = (int)(staging_nd[off + i] >> 20);
                atomicAdd(&cur[sl], 1);
            }
        }
        __syncthreads();
        if (tid == 0) {
            int run = bbase_nd[k];
            for (int i = 0; i < NS; ++i) {
                int c = cur[i];
                cur[i] = run;
                nd_ptr[s0 + i] = run;
                run += c;
            }
        }
        __syncthreads();
        for (int b = tid; b < nblk; b += 256) {
            int c   = counts_nd[(size_t)b * nb_nd + k];
            int off = b * BIN_CH + boffs_nd[(size_t)b * nb_nd + k];
            for (int i = 0; i < c; ++i) {
                unsigned pv = staging_nd[off + i];
                int pos = atomicAdd(&cur[pv >> 20], 1);
                nd_he[pos] = (int)(pv & 0xFFFFFu);
            }
        }
    } else {
        // ---- gather_he path ----
        int h = (blockIdx.x - nb_nd) * 4 + (tid >> 6);
        if (h >= HE) return;
        unsigned lane = tid & 63;
        unsigned half = lane >> 5;
        unsigned q    = lane & 31;
        int beg = he_ptr[h], end = he_ptr[h + 1];
        float a0 = 0.f, a1 = 0.f, a2 = 0.f, a3 = 0.f;
        int p = beg;
        for (; p + 7 < end; p += 8) {
            unsigned nA = (unsigned)members[p     + half];
            unsigned nB = (unsigned)members[p + 2 + half];
            unsigned nC = (unsigned)members[p + 4 + half];
            unsigned nD = (unsigned)members[p + 6 + half];
            uint2 uA = K2[(nA << 5) + q];
            uint2 uB = K2[(nB << 5) + q];
            uint2 uC = K2[(nC << 5) + q];
            uint2 uD = K2[(nD << 5) + q];
            a0 += (bflo(uA.x) + bflo(uB.x)) + (bflo(uC.x) + bflo(uD.x));
            a1 += (bfhi(uA.x) + bfhi(uB.x)) + (bfhi(uC.x) + bfhi(uD.x));
            a2 += (bflo(uA.y) + bflo(uB.y)) + (bflo(uC.y) + bflo(uD.y));
            a3 += (bfhi(uA.y) + bfhi(uB.y)) + (bfhi(uC.y) + bfhi(uD.y));
        }
        for (; p < end; p += 2) {
            int pi = p + (int)half;
            bool valid = pi < end;
            unsigned nn = (unsigned)members[valid ? pi : beg];
            uint2 u = K2[(nn << 5) + q];
            float w = valid ? 1.f : 0.f;
            a0 += w * bflo(u.x);
            a1 += w * bfhi(u.x);
            a2 += w * bflo(u.y);
            a3 += w * bfhi(u.y);
        }
        a0 += __shfl_xor(a0, 32);
        a1 += __shfl_xor(a1, 32);
        a2 += __shfl_xor(a2, 32);
        a3 += __shfl_xor(a3, 32);
        if (half == 0)
            he_feat2[((unsigned)h << 5) + q] = make_uint2(packbf(a0, a1), packbf(a2, a3));
    }
}

// ---------------------------------------------------------------------------
// Stages 3-5 fused: per-node online softmax + weighted accumulate.
// Unmasked full 8-wide main loop + masked 4-wide tail (avg degree ~10:
// masked-slop was ~30% of the VALU issue).
// ---------------------------------------------------------------------------
__global__ void fused_attn(const uint2* __restrict__ Qb,
                           const uint2* __restrict__ he_feat2,
                           const int* __restrict__ node_ptr,
                           const int* __restrict__ hes,
                           uint2* __restrict__ node_out_bf, int N)
{
    const float SCL = 0.17677669529663687f * 1.4426950408889634f;
    const float NEG = -1e30f;
    int n = blockIdx.x * 4 + (threadIdx.x >> 6);
    if (n >= N) return;
    unsigned lane = threadIdx.x & 63;
    unsigned half = lane >> 5;
    unsigned q    = lane & 31;
    int beg = node_ptr[n], end = node_ptr[n + 1];
    uint2 qu = Qb[((unsigned)n << 5) + q];
    float4 q4;
    q4.x = bflo(qu.x) * SCL; q4.y = bfhi(qu.x) * SCL;
    q4.z = bflo(qu.y) * SCL; q4.w = bfhi(qu.y) * SCL;
    float m = NEG, s = 0.f;
    float a0 = 0.f, a1 = 0.f, a2 = 0.f, a3 = 0.f;

    int p = beg;
    // full unmasked 8-wide iterations (no bounds checks, no clamps)
    for (; p + 8 <= end; p += 8) {
        unsigned hA = (unsigned)hes[p     + (int)half];
        unsigned hB = (unsigned)hes[p + 2 + (int)half];
        unsigned hC = (unsigned)hes[p + 4 + (int)half];
        unsigned hD = (unsigned)hes[p + 6 + (int)half];
        uint2 uA = he_feat2[(hA << 5) + q];
        uint2 uB = he_feat2[(hB << 5) + q];
        uint2 uC = he_feat2[(hC << 5) + q];
        uint2 uD = he_feat2[(hD << 5) + q];
        float fA0 = bflo(uA.x), fA1 = bfhi(uA.x), fA2 = bflo(uA.y), fA3 = bfhi(uA.y);
        float fB0 = bflo(uB.x), fB1 = bfhi(uB.x), fB2 = bflo(uB.y), fB3 = bfhi(uB.y);
        float fC0 = bflo(uC.x), fC1 = bfhi(uC.x), fC2 = bflo(uC.y), fC3 = bfhi(uC.y);
        float fD0 = bflo(uD.x), fD1 = bfhi(uD.x), fD2 = bflo(uD.y), fD3 = bfhi(uD.y);
        float dA = q4.x * fA0 + q4.y * fA1 + q4.z * fA2 + q4.w * fA3;
        float dB = q4.x * fB0 + q4.y * fB1 + q4.z * fB2 + q4.w * fB3;
        float dC = q4.x * fC0 + q4.y * fC1 + q4.z * fC2 + q4.w * fC3;
        float dD = q4.x * fD0 + q4.y * fD1 + q4.z * fD2 + q4.w * fD3;
        dA = red8(dA); dB = red8(dB); dC = red8(dC); dD = red8(dD);
        float newm = fmaxf(m, fmaxf(fmaxf(dA, dB), fmaxf(dC, dD)));
        float scale = fexp2(m - newm);
        float wA = fexp2(dA - newm), wB = fexp2(dB - newm);
        float wC = fexp2(dC - newm), wD = fexp2(dD - newm);
        s  = s  * scale + ((wA + wB) + (wC + wD));
        a0 = a0 * scale + ((wA * fA0 + wB * fB0) + (wC * fC0 + wD * fD0));
        a1 = a1 * scale + ((wA * fA1 + wB * fB1) + (wC * fC1 + wD * fD1));
        a2 = a2 * scale + ((wA * fA2 + wB * fB2) + (wC * fC2 + wD * fD2));
        a3 = a3 * scale + ((wA * fA3 + wB * fB3) + (wC * fC3 + wD * fD3));
        m = newm;
    }
    // masked 4-wide tail (remaining < 8 entries; <= 2 iterations)
    for (; p < end; p += 4) {
        const int last = end - 1;
        int iA = p + (int)half, iB = p + 2 + (int)half;
        bool vA = iA <= last, vB = iB <= last;
        unsigned hA = (unsigned)hes[vA ? iA : last];
        unsigned hB = (unsigned)hes[vB ? iB : last];
        uint2 uA = he_feat2[(hA << 5) + q];
        uint2 uB = he_feat2[(hB << 5) + q];
        float fA0 = bflo(uA.x), fA1 = bfhi(uA.x), fA2 = bflo(uA.y), fA3 = bfhi(uA.y);
        float fB0 = bflo(uB.x), fB1 = bfhi(uB.x), fB2 = bflo(uB.y), fB3 = bfhi(uB.y);
        float dA = q4.x * fA0 + q4.y * fA1 + q4.z * fA2 + q4.w * fA3;
        float dB = q4.x * fB0 + q4.y * fB1 + q4.z * fB2 + q4.w * fB3;
        dA = red8(dA); dB = red8(dB);
        float aA = vA ? dA : NEG;
        float aB = vB ? dB : NEG;
        float newm = fmaxf(m, fmaxf(aA, aB));
        float scale = fexp2(m - newm);
        float wA = fexp2(aA - newm), wB = fexp2(aB - newm);
        s  = s  * scale + (wA + wB);
        a0 = a0 * scale + (wA * fA0 + wB * fB0);
        a1 = a1 * scale + (wA * fA1 + wB * fB1);
        a2 = a2 * scale + (wA * fA2 + wB * fB2);
        a3 = a3 * scale + (wA * fA3 + wB * fB3);
        m = newm;
    }

    float mo = __shfl_xor(m, 32);
    float so = __shfl_xor(s, 32);
    float b0 = __shfl_xor(a0, 32);
    float b1 = __shfl_xor(a1, 32);
    float b2 = __shfl_xor(a2, 32);
    float b3 = __shfl_xor(a3, 32);
    float M  = fmaxf(m, mo);
    float e1 = fexp2(m - M), e2 = fexp2(mo - M);
    float S  = s * e1 + so * e2;
    float inv = 1.f / (S + 1e-16f);
    if (half == 0) {
        float o0 = (a0 * e1 + b0 * e2) * inv;
        float o1 = (a1 * e1 + b1 * e2) * inv;
        float o2 = (a2 * e1 + b2 * e2) * inv;
        float o3 = (a3 * e1 + b3 * e2) * inv;
        node_out_bf[((unsigned)n << 5) + q] = make_uint2(packbf(o0, o1), packbf(o2, o3));
    }
}

// ---------------------------------------------------------------------------
extern "C" void kernel_launch(void* const* d_in, const int* in_sizes, int n_in,
                              void* d_out, int out_size, void* d_ws, size_t ws_size,
                              hipStream_t stream)
{
    const float* x        = (const float*)d_in[0];
    const int*   node_idx = (const int*)d_in[1];
    const int*   he_idx   = (const int*)d_in[2];
    const float* Wk       = (const float*)d_in[3];
    const float* bk       = (const float*)d_in[4];
    const float* Wq       = (const float*)d_in[5];
    const float* bq       = (const float*)d_in[6];
    const float* Wa       = (const float*)d_in[7];
    const float* ba       = (const float*)d_in[8];
    float*       out      = (float*)d_out;

    const int N = in_sizes[0] / D;
    const int E = in_sizes[1];

    const int nblk  = (E + BIN_CH - 1) / BIN_CH;
    const int nb_he = (NUM_HE + 31) >> 5;    // 625 buckets of 32 hyperedges
    const int nb_nd = (N + 127) >> 7;        // 782 buckets of 128 nodes
    const int ggrid = (N + 127) / 128;

    // Workspace layout.
    float* ws      = (float*)d_ws;
    float* Kbuf    = ws;                               // N*D region: bf16 K, later bf16 node_out
    float* Qbuf    = Kbuf    + (size_t)N * D;          // N*D region (bf16 Q in half)
    float* he_feat = Qbuf    + (size_t)N * D;          // NUM_HE*D region (bf16 in half)
    unsigned short* wfrag = (unsigned short*)(he_feat + (size_t)NUM_HE * D); // 3*32768
    int*   ibase     = (int*)(wfrag + 3 * 32768);
    int*   he_ptr    = ibase;                            // NUM_HE+1
    int*   nd_ptr    = he_ptr    + (NUM_HE + 1);         // N+1
    int*   he_mem    = nd_ptr    + (N + 1);              // E (node ids by he)
    int*   nd_he     = he_mem    + E;                    // E (he ids by node)
    int*   counts_he = nd_he     + E;                    // nblk*nb_he
    int*   boffs_he  = counts_he + (size_t)nblk * nb_he; // nblk*nb_he
    int*   counts_nd = boffs_he  + (size_t)nblk * nb_he; // nblk*nb_nd
    int*   boffs_nd  = counts_nd + (size_t)nblk * nb_nd; // nblk*nb_nd
    int*   btot      = boffs_nd  + (size_t)nblk * nb_nd; // nb_he+nb_nd
    int*   bbase     = btot      + (nb_he + nb_nd);      // nb_he+nb_nd
    unsigned* staging_he = (unsigned*)(bbase + (nb_he + nb_nd)); // E
    unsigned* staging_nd = staging_he + E;                        // E

    // W fragments (hi/lo) for all three projections
    wprep<<<(3 * 16384 + 255) / 256, 256, 0, stream>>>(Wk, Wq, Wa, wfrag);

    // Stage 1 + binning fused: gemm blocks ++ binning blocks (independent)
    gemm_kq_stage<<<ggrid + nblk, 256, 0, stream>>>(
        x, wfrag, wfrag + 32768, wfrag + 49152,
        bk, bq, (unsigned short*)Kbuf, (unsigned short*)Qbuf, N, ggrid,
        he_idx, node_idx,
        counts_he, boffs_he, staging_he,
        counts_nd, boffs_nd, staging_nd, E, nb_he, nb_nd);

    bucket_tot2<<<(nb_he + nb_nd + 3) / 4, 256, 0, stream>>>(
        counts_he, counts_nd, btot, nb_he, nb_nd, nblk);
    bucket_scan2<<<2, 1024, 0, stream>>>(
        btot, bbase, he_ptr, nd_ptr, NUM_HE, N, nb_he, nb_nd, E);

    // he-side CSR fill
    fill_csr<5><<<nb_he, 256, 0, stream>>>(
        staging_he, counts_he, boffs_he, bbase, he_ptr, he_mem, NUM_HE, nb_he, nblk);

    // Fused: nd-side CSR fill ++ he-gather (independent)
    fill7_gather<<<nb_nd + (NUM_HE + 3) / 4, 256, 0, stream>>>(
        staging_nd, counts_nd, boffs_nd, bbase + nb_he, nd_ptr, nd_he,
        N, nb_nd, nblk,
        (const uint2*)Kbuf, he_ptr, he_mem, (uint2*)he_feat, NUM_HE);

    // Stages 3-5: fused attention (bf16 K dead; Kbuf region becomes bf16 node_out)
    fused_attn<<<(N + 3) / 4, 256, 0, stream>>>(
        (const uint2*)Qbuf, (const uint2*)he_feat, nd_ptr, nd_he, (uint2*)Kbuf, N);

    // Stage 6: residual (x fp32) + bf16 node_out @ Wa
    gemm_out<<<(N + 127) / 128, 256, 0, stream>>>(
        (const unsigned short*)Kbuf, x, wfrag + 65536, wfrag + 81920, ba, out, N);
}